// Round 5
// baseline (240.297 us; speedup 1.0000x reference)
//
#include <hip/hip_runtime.h>
#include <hip/hip_bf16.h>
#include <math.h>

// Problem constants
#define Bn   32
#define Cn   684
#define Hn   16
#define Wn   64
#define HWn  1024
#define HIDn 256
#define An   512
#define KKn  121           // 11*11
#define CREAL 805          // 684 + 121
#define CPAD 832           // 26 chunks of 32
#define NSTEP 26
#define NBLK 256           // a-columns per energy block (N-split x2)

// Output layout (flat fp32): context [32,684] | alpha [32,1024] | alpha_sum_new [32,1024]
#define OUT_ALPHA 21888
#define OUT_ASUM  (21888 + 32768)

typedef short short8 __attribute__((ext_vector_type(8)));     // 8 bf16 = 4 VGPRs
typedef float floatx4 __attribute__((ext_vector_type(4)));    // MFMA acc

__device__ __forceinline__ unsigned short f2bf(float f) {
    union { float f; unsigned int i; } v; v.f = f;
    unsigned int i = v.i;
    return (unsigned short)((i + 0x7fffu + ((i >> 16) & 1u)) >> 16);
}
// f32 pair -> packed bf16 (RTNE), lowers to v_cvt_pk_bf16_f32 on gfx950
__device__ __forceinline__ unsigned int cvt2(float lo, float hi) {
    __hip_bfloat162 h = __float22bfloat162_rn(float2{lo, hi});
    union { __hip_bfloat162 h; unsigned int u; } cv; cv.h = h;
    return cv.u;
}

// Bfr fragment-order index: element (n, k) -> short index.
// Wave reads 16B at block ((n>>4)*26 + (k>>5)), lane offset ((k>>3)&3)*16 + (n&15).
__device__ __forceinline__ size_t bfr_idx(int n, int k) {
    return ((((size_t)(n >> 4) * 26 + (k >> 5)) * 64
             + ((k >> 3) & 3) * 16 + (n & 15)) * 8) + (k & 7);
}

// ---------------------------------------------------------------------------
// K_prep: blocks 0..511 build Bfr row a (fragment-ordered); 512..543: query b;
// 544..575: zero energy for batch b (replaces hipMemsetAsync dispatch).
__global__ __launch_bounds__(256) void k_prep(
    const float* __restrict__ hidden,
    const float* __restrict__ Wh,
    const float* __restrict__ bh,
    const float* __restrict__ bec,
    const float* __restrict__ Wec,
    const float* __restrict__ Wac,
    const float* __restrict__ Waw,
    float* __restrict__ query,
    unsigned short* __restrict__ Bfr,
    float* __restrict__ energy)
{
    __shared__ float sbuf[512];
    const int blk = blockIdx.x, t = threadIdx.x;
    if (blk < 512) {
        const int a = blk;
        sbuf[t]       = Waw[(size_t)a * 512 + t];
        sbuf[t + 256] = Waw[(size_t)a * 512 + t + 256];
        __syncthreads();
        for (int cp = t; cp < Cn; cp += 256)
            Bfr[bfr_idx(a, cp)] = f2bf(Wec[(size_t)a * Cn + cp]);
        if (t < KKn) {
            float s = 0.f;
            #pragma unroll 8
            for (int k = 0; k < 512; ++k)
                s = fmaf(sbuf[k], Wac[k * KKn + t], s);
            Bfr[bfr_idx(a, Cn + t)] = f2bf(s);
        }
        for (int cp = CREAL + t; cp < CPAD; cp += 256)
            Bfr[bfr_idx(a, cp)] = 0;
    } else if (blk < 544) {
        const int b = blk - 512;
        sbuf[t] = (t < HIDn) ? hidden[b * HIDn + t] : 0.f;
        __syncthreads();
        for (int a = t; a < An; a += 256) {
            const float4* wp = (const float4*)(Wh + (size_t)a * HIDn);
            float s = bh[a] + bec[a];
            #pragma unroll 8
            for (int i = 0; i < HIDn / 4; ++i) {
                float4 w = wp[i];
                s = fmaf(sbuf[4 * i],     w.x, s);
                s = fmaf(sbuf[4 * i + 1], w.y, s);
                s = fmaf(sbuf[4 * i + 2], w.z, s);
                s = fmaf(sbuf[4 * i + 3], w.w, s);
            }
            query[b * An + a] = s;
        }
    } else {
        const int b = blk - 544;
        #pragma unroll
        for (int i = 0; i < 4; ++i)
            energy[b * HWn + i * 256 + t] = 0.f;
    }
}

// ---------------------------------------------------------------------------
// K_energy v9: v8 + counted-vmcnt pipeline (no vmcnt drain in the loop).
//  - Loop barrier = raw s_barrier preceded by lgkmcnt(0) ONLY (inline asm,
//    sched_barrier(0) fences per rule #18). __syncthreads()'s vmcnt(0)
//    drain was the 66%-idle cost in v8 (3.5K cyc/chunk vs 156 of MFMA).
//  - bf(ch+1) and va(ch+2) issued early in chunk ch (bf FIRST so the MFMA
//    wait doesn't chain on the slower X loads), consumed one chunk later;
//    compiler emits counted vmcnt for the register deps.
//  - Named ping-pong reg sets via unroll-2 (rule #20: no runtime-indexed
//    private arrays). Tail chunks use clamped indices -> loads resolve in
//    the zero-padded plane (in-bounds, discarded).
//  - Everything else = v8 (8 waves, nf=2, B-in-regs, LDS LUT im2col,
//    XCD-pair swizzle, spill-free at (512,4)).
__global__ __launch_bounds__(512, 4) void k_energy(
    const float* __restrict__ X,
    const float* __restrict__ asum,
    const float* __restrict__ Wv,
    const float* __restrict__ query,
    const unsigned short* __restrict__ Bfr,
    float* __restrict__ energy)
{
    __shared__ __align__(16) unsigned short As[2][64 * 40];   // 10,240B, stride 40
    __shared__ float plane[878];          // 814 im2col + 64 zero pad
    __shared__ int   lut[148];            // row-684 -> plane offset (or pad)
    __shared__ float qs[NBLK];
    __shared__ float wvs[NBLK];
    __shared__ float red[8][64];

    const int t = threadIdx.x;
    const int d = blockIdx.x;
    const int nh  = (d >> 3) & 1;
    const int pid = (d >> 4) * 8 + (d & 7);
    const int hh = pid & 15, b = pid >> 4;
    const int w = t >> 6, lane = t & 63;
    const int q = lane >> 4, r = lane & 15;
    const int nbase = nh * NBLK;
    const int mA = lane;                   // staging: m index; wave w -> k rows w*4..w*4+3

    const float* Xb = X + (size_t)b * Cn * HWn + hh * Wn;
    const unsigned short* Bp = Bfr + (size_t)(nh * 16 + w * 2) * 26 * 512;

    // ---- prologue: plane(+zero pad) / lut / qs / wvs / chunk 0
    for (int i = t; i < 878; i += 512) {
        float v = 0.f;
        if (i < 814) {
            int di = i / 74, cc = i - di * 74;
            int h2 = hh + di - 5, w2 = cc - 5;
            if (h2 >= 0 && h2 < Hn && w2 >= 0 && w2 < Wn)
                v = asum[b * HWn + h2 * Wn + w2];
        }
        plane[i] = v;
    }
    if (t < 148) {
        int off = 814;                    // zero-pad region
        if (t < 121) { int di = t / 11; off = di * 74 + (t - di * 11); }
        lut[t] = off;
    }
    if (t < NBLK) {
        qs[t]  = query[b * An + nbase + t];
        wvs[t] = Wv[nbase + t];
    }
    // stage A chunk 0: wave w loads rows w*4..w*4+3 (pure X)
    {
        const float* xp = Xb + (size_t)(w * 4) * HWn + mA;
        float v0 = xp[0];
        float v1 = xp[(size_t)1 * HWn];
        float v2 = xp[(size_t)2 * HWn];
        float v3 = xp[(size_t)3 * HWn];
        *(uint2*)&As[0][mA * 40 + w * 4] = make_uint2(cvt2(v0, v1), cvt2(v2, v3));
    }

    short8 bfA[2], bfB[2];
    float vaA[4], vaB[4];

    // prefetch bf(0) and va(chunk 1 data, rows 32..63 pure X)
    #pragma unroll
    for (int nf = 0; nf < 2; ++nf)
        bfA[nf] = *(const short8*)(Bp + ((size_t)(nf * 26)) * 512 + lane * 8);
    {
        const float* xp = Xb + (size_t)(32 + w * 4) * HWn + mA;
        vaA[0] = xp[0];
        vaA[1] = xp[(size_t)1 * HWn];
        vaA[2] = xp[(size_t)2 * HWn];
        vaA[3] = xp[(size_t)3 * HWn];
    }
    __syncthreads();   // prologue: full drain once is fine

    floatx4 acc[4][2];
    #pragma unroll
    for (int mf = 0; mf < 4; ++mf)
        #pragma unroll
        for (int nf = 0; nf < 2; ++nf)
            acc[mf][nf] = (floatx4){0.f, 0.f, 0.f, 0.f};

#define ISSUE_BF(DST, CC) {                                                   \
    const int cb_ = (CC) <= 25 ? (CC) : 25;                                   \
    _Pragma("unroll")                                                         \
    for (int nf = 0; nf < 2; ++nf)                                            \
        DST[nf] = *(const short8*)(Bp + ((size_t)(nf * 26 + cb_)) * 512       \
                                      + lane * 8);                            \
    }

#define ISSUE_VA(DST, CC) {                                                   \
    const int cc_ = (CC) <= 25 ? (CC) : 25;                                   \
    const int c0_ = cc_ * 32 + w * 4;                                         \
    _Pragma("unroll")                                                         \
    for (int j = 0; j < 4; ++j) {                                             \
        const int row = c0_ + j;                                              \
        if (row < Cn) DST[j] = Xb[(size_t)row * HWn + mA];                    \
        else          DST[j] = plane[lut[row - Cn] + mA];                     \
    } }

#define READA(CUR) {                                                          \
    _Pragma("unroll")                                                         \
    for (int mf = 0; mf < 4; ++mf)                                            \
        af[mf] = *(const short8*)&As[CUR][(mf * 16 + r) * 40 + q * 8];        \
    }

#define MFMA8(BF) {                                                           \
    _Pragma("unroll")                                                         \
    for (int mf = 0; mf < 4; ++mf)                                            \
        _Pragma("unroll")                                                     \
        for (int nf = 0; nf < 2; ++nf)                                        \
            acc[mf][nf] = __builtin_amdgcn_mfma_f32_16x16x32_bf16(            \
                af[mf], BF[nf], acc[mf][nf], 0, 0, 0);                        \
    }

#define WRITEA(CUR, SRC) {                                                    \
    *(uint2*)&As[CUR][mA * 40 + w * 4] =                                      \
        make_uint2(cvt2(SRC[0], SRC[1]), cvt2(SRC[2], SRC[3]));               \
    }

#define LOOP_BARRIER() {                                                      \
    asm volatile("s_waitcnt lgkmcnt(0)" ::: "memory");                        \
    __builtin_amdgcn_sched_barrier(0);                                        \
    __builtin_amdgcn_s_barrier();                                             \
    __builtin_amdgcn_sched_barrier(0);                                        \
    }

    short8 af[4];
    for (int ch = 0; ch < NSTEP; ch += 2) {
        // ---- even chunk ch: read As[0]/bfA; write vaA (ch+1 data) -> As[1]
        READA(0);
        ISSUE_BF(bfB, ch + 1);            // bf first: MFMA wait won't chain on X
        ISSUE_VA(vaB, ch + 2);
        MFMA8(bfA);
        WRITEA(1, vaA);                   // counted vmcnt lands here (~1 chunk old)
        LOOP_BARRIER();

        // ---- odd chunk ch+1: read As[1]/bfB; write vaB (ch+2 data) -> As[0]
        READA(1);
        ISSUE_BF(bfA, ch + 2);
        ISSUE_VA(vaA, ch + 3);
        MFMA8(bfB);
        if (ch + 2 < NSTEP) WRITEA(0, vaB);
        LOOP_BARRIER();
    }

#undef ISSUE_BF
#undef ISSUE_VA
#undef READA
#undef MFMA8
#undef WRITEA
#undef LOOP_BARRIER

    // ---- epilogue: e[m] = sum_n Wv[n]*tanh(acc + query[n])
    float ep[16];
    #pragma unroll
    for (int i = 0; i < 16; ++i) ep[i] = 0.f;
    #pragma unroll
    for (int nf = 0; nf < 2; ++nf) {
        int nl = w * 32 + nf * 16 + r;
        float qv = qs[nl], wv = wvs[nl];
        #pragma unroll
        for (int mf = 0; mf < 4; ++mf)
            #pragma unroll
            for (int rg = 0; rg < 4; ++rg) {
                float x = acc[mf][nf][rg] + qv;
                float e2 = __expf(2.f * x);
                float th = 1.f - 2.f * __builtin_amdgcn_rcpf(e2 + 1.f);
                ep[mf * 4 + rg] += wv * th;
            }
    }
    // reduce over the 16 r-lanes (lane bits 0..3) via shfl_xor
    #pragma unroll
    for (int i = 0; i < 16; ++i) {
        #pragma unroll
        for (int msk = 1; msk <= 8; msk <<= 1)
            ep[i] += __shfl_xor(ep[i], msk, 64);
    }
    if (r == 0) {
        #pragma unroll
        for (int mf = 0; mf < 4; ++mf)
            #pragma unroll
            for (int rg = 0; rg < 4; ++rg)
                red[w][mf * 16 + q * 4 + rg] = ep[mf * 4 + rg];
    }
    __syncthreads();
    if (t < 64) {
        float s = 0.f;
        #pragma unroll
        for (int ww = 0; ww < 8; ++ww) s += red[ww][t];
        atomicAdd(&energy[b * HWn + hh * Wn + t], s);
    }
}

// ---------------------------------------------------------------------------
// K_softmax: one block per batch. alpha from energy once, written in-place
// over energy, plus alpha / alpha_sum_new outputs.
__global__ __launch_bounds__(256) void k_softmax(
    const float* __restrict__ mask,
    const float* __restrict__ asum,
    float* __restrict__ energy,     // in: energy, out: alpha
    float* __restrict__ out)
{
    __shared__ float rsm[8];
    const int b = blockIdx.x;
    const int t = threadIdx.x, lane = t & 63, wid = t >> 6;

    float e[4], ex[4];
    #pragma unroll
    for (int i = 0; i < 4; ++i) e[i] = energy[b * HWn + i * 256 + t];
    float m = fmaxf(fmaxf(e[0], e[1]), fmaxf(e[2], e[3]));
    for (int off = 32; off >= 1; off >>= 1) m = fmaxf(m, __shfl_down(m, off, 64));
    if (lane == 0) rsm[wid] = m;
    __syncthreads();
    if (t == 0)
        rsm[4] = fmaxf(fmaxf(rsm[0], rsm[1]), fmaxf(rsm[2], rsm[3]));
    __syncthreads();
    const float M = rsm[4];
    float s = 0.f;
    #pragma unroll
    for (int i = 0; i < 4; ++i) {
        ex[i] = expf(e[i] - M) * mask[b * HWn + i * 256 + t];
        s += ex[i];
    }
    for (int off = 32; off >= 1; off >>= 1) s += __shfl_down(s, off, 64);
    __syncthreads();
    if (lane == 0) rsm[wid] = s;
    __syncthreads();
    if (t == 0) rsm[5] = rsm[0] + rsm[1] + rsm[2] + rsm[3] + 1e-10f;
    __syncthreads();
    const float denom = rsm[5];
    #pragma unroll
    for (int i = 0; i < 4; ++i) {
        int p = i * 256 + t;
        float a = ex[i] / denom;
        energy[b * HWn + p] = a;
        out[OUT_ALPHA + b * HWn + p] = a;
        out[OUT_ASUM  + b * HWn + p] = a + asum[b * HWn + p];
    }
}

// ---------------------------------------------------------------------------
// K_ctx: pure context GEMV. Grid (171, 32); block caches alpha in LDS,
// wave wid handles channel bx*4+wid. Streams X once.
__global__ __launch_bounds__(256) void k_ctx(
    const float* __restrict__ X,
    const float* __restrict__ alpha,
    float* __restrict__ out)
{
    __shared__ float al[1024];
    const int bx = blockIdx.x, b = blockIdx.y;
    const int t = threadIdx.x, lane = t & 63, wid = t >> 6;

    #pragma unroll
    for (int i = 0; i < 4; ++i) al[i * 256 + t] = alpha[b * HWn + i * 256 + t];
    __syncthreads();

    const int c = bx * 4 + wid;
    const float* xp = X + ((size_t)(b * Cn + c)) * HWn;
    float s2 = 0.f;
    #pragma unroll
    for (int i = 0; i < 4; ++i) {
        int off = i * 256 + lane * 4;
        float4 x = *(const float4*)(xp + off);
        float4 a = *(const float4*)(al + off);
        s2 = fmaf(a.x, x.x, s2);
        s2 = fmaf(a.y, x.y, s2);
        s2 = fmaf(a.z, x.z, s2);
        s2 = fmaf(a.w, x.w, s2);
    }
    for (int off = 32; off >= 1; off >>= 1) s2 += __shfl_down(s2, off, 64);
    if (lane == 0) out[b * Cn + c] = s2;
}

// ---------------------------------------------------------------------------
extern "C" void kernel_launch(void* const* d_in, const int* in_sizes, int n_in,
                              void* d_out, int out_size, void* d_ws, size_t ws_size,
                              hipStream_t stream)
{
    const float* X      = (const float*)d_in[0];
    const float* hidden = (const float*)d_in[1];
    const float* asum   = (const float*)d_in[2];
    const float* mask   = (const float*)d_in[3];
    const float* Wh     = (const float*)d_in[4];
    const float* bh     = (const float*)d_in[5];
    const float* Wec    = (const float*)d_in[6];
    const float* bec    = (const float*)d_in[7];
    const float* Wac    = (const float*)d_in[8];
    const float* Waw    = (const float*)d_in[9];
    const float* Wv     = (const float*)d_in[10];
    (void)in_sizes; (void)n_in; (void)out_size; (void)ws_size;

    float* out = (float*)d_out;
    float* ws = (float*)d_ws;
    float* query  = ws;                                    // 16384 floats
    float* energy = ws + 16384;                            // 32768 (energy -> alpha)
    unsigned short* Bfr = (unsigned short*)(ws + 16384 + 32768); // 512*832 bf16

    k_prep    <<<dim3(576),      dim3(256), 0, stream>>>(hidden, Wh, bh, bec,
                                                         Wec, Wac, Waw, query, Bfr, energy);
    k_energy  <<<dim3(1024),     dim3(512), 0, stream>>>(X, asum, Wv, query, Bfr, energy);
    k_softmax <<<dim3(32),       dim3(256), 0, stream>>>(mask, asum, energy, out);
    k_ctx     <<<dim3(171, 32),  dim3(256), 0, stream>>>(X, energy, out);
}

// Round 6
// 232.851 us; speedup vs baseline: 1.0320x; 1.0320x over previous
//
#include <hip/hip_runtime.h>
#include <hip/hip_bf16.h>
#include <math.h>

// Problem constants
#define Bn   32
#define Cn   684
#define Hn   16
#define Wn   64
#define HWn  1024
#define HIDn 256
#define An   512
#define KKn  121           // 11*11
#define CREAL 805          // 684 + 121
#define CPAD 832           // 26 chunks of 32
#define NSTEP 26
#define NBLK 256           // a-columns per energy block (N-split x2)

// Output layout (flat fp32): context [32,684] | alpha [32,1024] | alpha_sum_new [32,1024]
#define OUT_ALPHA 21888
#define OUT_ASUM  (21888 + 32768)

typedef short short8 __attribute__((ext_vector_type(8)));     // 8 bf16 = 4 VGPRs
typedef float floatx4 __attribute__((ext_vector_type(4)));    // MFMA acc

__device__ __forceinline__ unsigned short f2bf(float f) {
    union { float f; unsigned int i; } v; v.f = f;
    unsigned int i = v.i;
    return (unsigned short)((i + 0x7fffu + ((i >> 16) & 1u)) >> 16);
}
// f32 pair -> packed bf16 (RTNE), lowers to v_cvt_pk_bf16_f32 on gfx950
__device__ __forceinline__ unsigned int cvt2(float lo, float hi) {
    __hip_bfloat162 h = __float22bfloat162_rn(float2{lo, hi});
    union { __hip_bfloat162 h; unsigned int u; } cv; cv.h = h;
    return cv.u;
}

// Bfr fragment-order index: element (n, k) -> short index.
// Wave reads 16B at block ((n>>4)*26 + (k>>5)), lane offset ((k>>3)&3)*16 + (n&15).
__device__ __forceinline__ size_t bfr_idx(int n, int k) {
    return ((((size_t)(n >> 4) * 26 + (k >> 5)) * 64
             + ((k >> 3) & 3) * 16 + (n & 15)) * 8) + (k & 7);
}

// ---------------------------------------------------------------------------
// K_prep: blocks 0..511 build Bfr row a (fragment-ordered); 512..543: query b;
// 544..575: zero energy for batch b (replaces hipMemsetAsync dispatch).
__global__ __launch_bounds__(256) void k_prep(
    const float* __restrict__ hidden,
    const float* __restrict__ Wh,
    const float* __restrict__ bh,
    const float* __restrict__ bec,
    const float* __restrict__ Wec,
    const float* __restrict__ Wac,
    const float* __restrict__ Waw,
    float* __restrict__ query,
    unsigned short* __restrict__ Bfr,
    float* __restrict__ energy)
{
    __shared__ float sbuf[512];
    const int blk = blockIdx.x, t = threadIdx.x;
    if (blk < 512) {
        const int a = blk;
        sbuf[t]       = Waw[(size_t)a * 512 + t];
        sbuf[t + 256] = Waw[(size_t)a * 512 + t + 256];
        __syncthreads();
        for (int cp = t; cp < Cn; cp += 256)
            Bfr[bfr_idx(a, cp)] = f2bf(Wec[(size_t)a * Cn + cp]);
        if (t < KKn) {
            float s = 0.f;
            #pragma unroll 8
            for (int k = 0; k < 512; ++k)
                s = fmaf(sbuf[k], Wac[k * KKn + t], s);
            Bfr[bfr_idx(a, Cn + t)] = f2bf(s);
        }
        for (int cp = CREAL + t; cp < CPAD; cp += 256)
            Bfr[bfr_idx(a, cp)] = 0;
    } else if (blk < 544) {
        const int b = blk - 512;
        sbuf[t] = (t < HIDn) ? hidden[b * HIDn + t] : 0.f;
        __syncthreads();
        for (int a = t; a < An; a += 256) {
            const float4* wp = (const float4*)(Wh + (size_t)a * HIDn);
            float s = bh[a] + bec[a];
            #pragma unroll 8
            for (int i = 0; i < HIDn / 4; ++i) {
                float4 w = wp[i];
                s = fmaf(sbuf[4 * i],     w.x, s);
                s = fmaf(sbuf[4 * i + 1], w.y, s);
                s = fmaf(sbuf[4 * i + 2], w.z, s);
                s = fmaf(sbuf[4 * i + 3], w.w, s);
            }
            query[b * An + a] = s;
        }
    } else {
        const int b = blk - 544;
        #pragma unroll
        for (int i = 0; i < 4; ++i)
            energy[b * HWn + i * 256 + t] = 0.f;
    }
}

// ---------------------------------------------------------------------------
// K_energy v10: v9 + TRUE 2-phase-deep prefetch + setprio.
//  - v9's flaw: vaB issued in even phase was consumed by WRITEA in the SAME
//    iteration's odd phase (~1/2 chunk of cover vs ~600-900cy X latency);
//    bf was 1 phase deep. Every phase still exposed most of an HBM latency.
//  - Now each named reg set lives 2 phases: phase p consumes set (issued at
//    p-2), THEN reissues it for p+2. Order: READA -> WRITEA(va, 2ph old) ->
//    MFMA(bf, 2ph old) -> reissue bf(ch+2), va(ch+3) -> lgkm-only barrier.
//    bf loads always issue before va loads, so WRITEA's counted vmcnt
//    auto-retires bf before the MFMA (no drain, no chain on X).
//  - T5: s_setprio(1) around MFMA (phase-split wave roles now exist).
//  - Everything else = v8/v9 (8 waves, nf=2, B-in-regs, LDS LUT im2col,
//    XCD-pair swizzle, spill-free, lgkmcnt-only loop barrier per rule #18).
__global__ __launch_bounds__(512, 4) void k_energy(
    const float* __restrict__ X,
    const float* __restrict__ asum,
    const float* __restrict__ Wv,
    const float* __restrict__ query,
    const unsigned short* __restrict__ Bfr,
    float* __restrict__ energy)
{
    __shared__ __align__(16) unsigned short As[2][64 * 40];   // 10,240B, stride 40
    __shared__ float plane[878];          // 814 im2col + 64 zero pad
    __shared__ int   lut[148];            // row-684 -> plane offset (or pad)
    __shared__ float qs[NBLK];
    __shared__ float wvs[NBLK];
    __shared__ float red[8][64];

    const int t = threadIdx.x;
    const int d = blockIdx.x;
    const int nh  = (d >> 3) & 1;
    const int pid = (d >> 4) * 8 + (d & 7);
    const int hh = pid & 15, b = pid >> 4;
    const int w = t >> 6, lane = t & 63;
    const int q = lane >> 4, r = lane & 15;
    const int nbase = nh * NBLK;
    const int mA = lane;                   // staging: m index; wave w -> k rows w*4..w*4+3

    const float* Xb = X + (size_t)b * Cn * HWn + hh * Wn;
    const unsigned short* Bp = Bfr + (size_t)(nh * 16 + w * 2) * 26 * 512;

    // ---- prologue: plane(+zero pad) / lut / qs / wvs / chunk 0
    for (int i = t; i < 878; i += 512) {
        float v = 0.f;
        if (i < 814) {
            int di = i / 74, cc = i - di * 74;
            int h2 = hh + di - 5, w2 = cc - 5;
            if (h2 >= 0 && h2 < Hn && w2 >= 0 && w2 < Wn)
                v = asum[b * HWn + h2 * Wn + w2];
        }
        plane[i] = v;
    }
    if (t < 148) {
        int off = 814;                    // zero-pad region
        if (t < 121) { int di = t / 11; off = di * 74 + (t - di * 11); }
        lut[t] = off;
    }
    if (t < NBLK) {
        qs[t]  = query[b * An + nbase + t];
        wvs[t] = Wv[nbase + t];
    }
    // stage A chunk 0: wave w loads rows w*4..w*4+3 (pure X)
    {
        const float* xp = Xb + (size_t)(w * 4) * HWn + mA;
        float v0 = xp[0];
        float v1 = xp[(size_t)1 * HWn];
        float v2 = xp[(size_t)2 * HWn];
        float v3 = xp[(size_t)3 * HWn];
        *(uint2*)&As[0][mA * 40 + w * 4] = make_uint2(cvt2(v0, v1), cvt2(v2, v3));
    }

    short8 bfA[2], bfB[2];
    float vaA[4], vaB[4];

    // prefetch 2 phases deep: bfA=bf(0), bfB=bf(1), vaA=data(1), vaB=data(2)
    #pragma unroll
    for (int nf = 0; nf < 2; ++nf)
        bfA[nf] = *(const short8*)(Bp + ((size_t)(nf * 26 + 0)) * 512 + lane * 8);
    #pragma unroll
    for (int nf = 0; nf < 2; ++nf)
        bfB[nf] = *(const short8*)(Bp + ((size_t)(nf * 26 + 1)) * 512 + lane * 8);
    {
        const float* xp = Xb + (size_t)(32 + w * 4) * HWn + mA;
        vaA[0] = xp[0];
        vaA[1] = xp[(size_t)1 * HWn];
        vaA[2] = xp[(size_t)2 * HWn];
        vaA[3] = xp[(size_t)3 * HWn];
    }
    {
        const float* xp = Xb + (size_t)(64 + w * 4) * HWn + mA;
        vaB[0] = xp[0];
        vaB[1] = xp[(size_t)1 * HWn];
        vaB[2] = xp[(size_t)2 * HWn];
        vaB[3] = xp[(size_t)3 * HWn];
    }
    __syncthreads();   // prologue: full drain once is fine

    floatx4 acc[4][2];
    #pragma unroll
    for (int mf = 0; mf < 4; ++mf)
        #pragma unroll
        for (int nf = 0; nf < 2; ++nf)
            acc[mf][nf] = (floatx4){0.f, 0.f, 0.f, 0.f};

#define ISSUE_BF(DST, CC) {                                                   \
    const int cb_ = (CC) <= 25 ? (CC) : 25;                                   \
    _Pragma("unroll")                                                         \
    for (int nf = 0; nf < 2; ++nf)                                            \
        DST[nf] = *(const short8*)(Bp + ((size_t)(nf * 26 + cb_)) * 512       \
                                      + lane * 8);                            \
    }

#define ISSUE_VA(DST, CC) {                                                   \
    const int cc_ = (CC) <= 25 ? (CC) : 25;                                   \
    const int c0_ = cc_ * 32 + w * 4;                                         \
    _Pragma("unroll")                                                         \
    for (int j = 0; j < 4; ++j) {                                             \
        const int row = c0_ + j;                                              \
        if (row < Cn) DST[j] = Xb[(size_t)row * HWn + mA];                    \
        else          DST[j] = plane[lut[row - Cn] + mA];                     \
    } }

#define READA(CUR) {                                                          \
    _Pragma("unroll")                                                         \
    for (int mf = 0; mf < 4; ++mf)                                            \
        af[mf] = *(const short8*)&As[CUR][(mf * 16 + r) * 40 + q * 8];        \
    }

#define MFMA8(BF) {                                                           \
    __builtin_amdgcn_s_setprio(1);                                            \
    _Pragma("unroll")                                                         \
    for (int mf = 0; mf < 4; ++mf)                                            \
        _Pragma("unroll")                                                     \
        for (int nf = 0; nf < 2; ++nf)                                        \
            acc[mf][nf] = __builtin_amdgcn_mfma_f32_16x16x32_bf16(            \
                af[mf], BF[nf], acc[mf][nf], 0, 0, 0);                        \
    __builtin_amdgcn_s_setprio(0);                                            \
    }

#define WRITEA(CUR, SRC) {                                                    \
    *(uint2*)&As[CUR][mA * 40 + w * 4] =                                      \
        make_uint2(cvt2(SRC[0], SRC[1]), cvt2(SRC[2], SRC[3]));               \
    }

#define LOOP_BARRIER() {                                                      \
    asm volatile("s_waitcnt lgkmcnt(0)" ::: "memory");                        \
    __builtin_amdgcn_sched_barrier(0);                                        \
    __builtin_amdgcn_s_barrier();                                             \
    __builtin_amdgcn_sched_barrier(0);                                        \
    }

    short8 af[4];
    for (int ch = 0; ch < NSTEP; ch += 2) {
        // ---- even phase: chunk ch from buf0; vaA/bfA are 2 phases old
        READA(0);
        WRITEA(1, vaA);                   // data(ch+1) -> buf1 (covered latency)
        MFMA8(bfA);                       // bf(ch): older than vaA's loads -> no extra wait
        ISSUE_BF(bfA, ch + 2);            // consumed at phase ch+2 (2 deep)
        ISSUE_VA(vaA, ch + 3);            // consumed at phase ch+2's WRITEA (2 deep)
        LOOP_BARRIER();

        // ---- odd phase: chunk ch+1 from buf1; vaB/bfB are 2 phases old
        READA(1);
        WRITEA(0, vaB);                   // data(ch+2) -> buf0
        MFMA8(bfB);                       // bf(ch+1)
        ISSUE_BF(bfB, ch + 3);
        ISSUE_VA(vaB, ch + 4);
        LOOP_BARRIER();
    }

#undef ISSUE_BF
#undef ISSUE_VA
#undef READA
#undef MFMA8
#undef WRITEA
#undef LOOP_BARRIER

    // ---- epilogue: e[m] = sum_n Wv[n]*tanh(acc + query[n])
    float ep[16];
    #pragma unroll
    for (int i = 0; i < 16; ++i) ep[i] = 0.f;
    #pragma unroll
    for (int nf = 0; nf < 2; ++nf) {
        int nl = w * 32 + nf * 16 + r;
        float qv = qs[nl], wv = wvs[nl];
        #pragma unroll
        for (int mf = 0; mf < 4; ++mf)
            #pragma unroll
            for (int rg = 0; rg < 4; ++rg) {
                float x = acc[mf][nf][rg] + qv;
                float e2 = __expf(2.f * x);
                float th = 1.f - 2.f * __builtin_amdgcn_rcpf(e2 + 1.f);
                ep[mf * 4 + rg] += wv * th;
            }
    }
    // reduce over the 16 r-lanes (lane bits 0..3) via shfl_xor
    #pragma unroll
    for (int i = 0; i < 16; ++i) {
        #pragma unroll
        for (int msk = 1; msk <= 8; msk <<= 1)
            ep[i] += __shfl_xor(ep[i], msk, 64);
    }
    if (r == 0) {
        #pragma unroll
        for (int mf = 0; mf < 4; ++mf)
            #pragma unroll
            for (int rg = 0; rg < 4; ++rg)
                red[w][mf * 16 + q * 4 + rg] = ep[mf * 4 + rg];
    }
    __syncthreads();
    if (t < 64) {
        float s = 0.f;
        #pragma unroll
        for (int ww = 0; ww < 8; ++ww) s += red[ww][t];
        atomicAdd(&energy[b * HWn + hh * Wn + t], s);
    }
}

// ---------------------------------------------------------------------------
// K_softmax: one block per batch. alpha from energy once, written in-place
// over energy, plus alpha / alpha_sum_new outputs.
__global__ __launch_bounds__(256) void k_softmax(
    const float* __restrict__ mask,
    const float* __restrict__ asum,
    float* __restrict__ energy,     // in: energy, out: alpha
    float* __restrict__ out)
{
    __shared__ float rsm[8];
    const int b = blockIdx.x;
    const int t = threadIdx.x, lane = t & 63, wid = t >> 6;

    float e[4], ex[4];
    #pragma unroll
    for (int i = 0; i < 4; ++i) e[i] = energy[b * HWn + i * 256 + t];
    float m = fmaxf(fmaxf(e[0], e[1]), fmaxf(e[2], e[3]));
    for (int off = 32; off >= 1; off >>= 1) m = fmaxf(m, __shfl_down(m, off, 64));
    if (lane == 0) rsm[wid] = m;
    __syncthreads();
    if (t == 0)
        rsm[4] = fmaxf(fmaxf(rsm[0], rsm[1]), fmaxf(rsm[2], rsm[3]));
    __syncthreads();
    const float M = rsm[4];
    float s = 0.f;
    #pragma unroll
    for (int i = 0; i < 4; ++i) {
        ex[i] = expf(e[i] - M) * mask[b * HWn + i * 256 + t];
        s += ex[i];
    }
    for (int off = 32; off >= 1; off >>= 1) s += __shfl_down(s, off, 64);
    __syncthreads();
    if (lane == 0) rsm[wid] = s;
    __syncthreads();
    if (t == 0) rsm[5] = rsm[0] + rsm[1] + rsm[2] + rsm[3] + 1e-10f;
    __syncthreads();
    const float denom = rsm[5];
    #pragma unroll
    for (int i = 0; i < 4; ++i) {
        int p = i * 256 + t;
        float a = ex[i] / denom;
        energy[b * HWn + p] = a;
        out[OUT_ALPHA + b * HWn + p] = a;
        out[OUT_ASUM  + b * HWn + p] = a + asum[b * HWn + p];
    }
}

// ---------------------------------------------------------------------------
// K_ctx: pure context GEMV. Grid (171, 32); block caches alpha in LDS,
// wave wid handles channel bx*4+wid. Streams X once.
__global__ __launch_bounds__(256) void k_ctx(
    const float* __restrict__ X,
    const float* __restrict__ alpha,
    float* __restrict__ out)
{
    __shared__ float al[1024];
    const int bx = blockIdx.x, b = blockIdx.y;
    const int t = threadIdx.x, lane = t & 63, wid = t >> 6;

    #pragma unroll
    for (int i = 0; i < 4; ++i) al[i * 256 + t] = alpha[b * HWn + i * 256 + t];
    __syncthreads();

    const int c = bx * 4 + wid;
    const float* xp = X + ((size_t)(b * Cn + c)) * HWn;
    float s2 = 0.f;
    #pragma unroll
    for (int i = 0; i < 4; ++i) {
        int off = i * 256 + lane * 4;
        float4 x = *(const float4*)(xp + off);
        float4 a = *(const float4*)(al + off);
        s2 = fmaf(a.x, x.x, s2);
        s2 = fmaf(a.y, x.y, s2);
        s2 = fmaf(a.z, x.z, s2);
        s2 = fmaf(a.w, x.w, s2);
    }
    for (int off = 32; off >= 1; off >>= 1) s2 += __shfl_down(s2, off, 64);
    if (lane == 0) out[b * Cn + c] = s2;
}

// ---------------------------------------------------------------------------
extern "C" void kernel_launch(void* const* d_in, const int* in_sizes, int n_in,
                              void* d_out, int out_size, void* d_ws, size_t ws_size,
                              hipStream_t stream)
{
    const float* X      = (const float*)d_in[0];
    const float* hidden = (const float*)d_in[1];
    const float* asum   = (const float*)d_in[2];
    const float* mask   = (const float*)d_in[3];
    const float* Wh     = (const float*)d_in[4];
    const float* bh     = (const float*)d_in[5];
    const float* Wec    = (const float*)d_in[6];
    const float* bec    = (const float*)d_in[7];
    const float* Wac    = (const float*)d_in[8];
    const float* Waw    = (const float*)d_in[9];
    const float* Wv     = (const float*)d_in[10];
    (void)in_sizes; (void)n_in; (void)out_size; (void)ws_size;

    float* out = (float*)d_out;
    float* ws = (float*)d_ws;
    float* query  = ws;                                    // 16384 floats
    float* energy = ws + 16384;                            // 32768 (energy -> alpha)
    unsigned short* Bfr = (unsigned short*)(ws + 16384 + 32768); // 512*832 bf16

    k_prep    <<<dim3(576),      dim3(256), 0, stream>>>(hidden, Wh, bh, bec,
                                                         Wec, Wac, Waw, query, Bfr, energy);
    k_energy  <<<dim3(1024),     dim3(512), 0, stream>>>(X, asum, Wv, query, Bfr, energy);
    k_softmax <<<dim3(32),       dim3(256), 0, stream>>>(mask, asum, energy, out);
    k_ctx     <<<dim3(171, 32),  dim3(256), 0, stream>>>(X, energy, out);
}

// Round 7
// 231.836 us; speedup vs baseline: 1.0365x; 1.0044x over previous
//
#include <hip/hip_runtime.h>
#include <hip/hip_bf16.h>
#include <math.h>

// Problem constants
#define Bn   32
#define Cn   684
#define Hn   16
#define Wn   64
#define HWn  1024
#define HIDn 256
#define An   512
#define KKn  121           // 11*11
#define CREAL 805          // 684 + 121
#define CPAD 832           // 26 chunks of 32
#define NSTEP 26

// Output layout (flat fp32): context [32,684] | alpha [32,1024] | alpha_sum_new [32,1024]
#define OUT_ALPHA 21888
#define OUT_ASUM  (21888 + 32768)

typedef short short8 __attribute__((ext_vector_type(8)));     // 8 bf16 = 4 VGPRs
typedef float floatx4 __attribute__((ext_vector_type(4)));    // MFMA acc

__device__ __forceinline__ unsigned short f2bf(float f) {
    union { float f; unsigned int i; } v; v.f = f;
    unsigned int i = v.i;
    return (unsigned short)((i + 0x7fffu + ((i >> 16) & 1u)) >> 16);
}
// f32 pair -> packed bf16 (RTNE), lowers to v_cvt_pk_bf16_f32 on gfx950
__device__ __forceinline__ unsigned int cvt2(float lo, float hi) {
    __hip_bfloat162 h = __float22bfloat162_rn(float2{lo, hi});
    union { __hip_bfloat162 h; unsigned int u; } cv; cv.h = h;
    return cv.u;
}

// Bfr fragment-order index: element (n, k) -> short index.
// Wave reads 16B at block ((n>>4)*26 + (k>>5)), lane offset ((k>>3)&3)*16 + (n&15).
__device__ __forceinline__ size_t bfr_idx(int n, int k) {
    return ((((size_t)(n >> 4) * 26 + (k >> 5)) * 64
             + ((k >> 3) & 3) * 16 + (n & 15)) * 8) + (k & 7);
}

// ---------------------------------------------------------------------------
// K_prep: blocks 0..511 build Bfr row a (fragment-ordered); 512..543: query b;
// 544..575: zero energy for batch b.
__global__ __launch_bounds__(256) void k_prep(
    const float* __restrict__ hidden,
    const float* __restrict__ Wh,
    const float* __restrict__ bh,
    const float* __restrict__ bec,
    const float* __restrict__ Wec,
    const float* __restrict__ Wac,
    const float* __restrict__ Waw,
    float* __restrict__ query,
    unsigned short* __restrict__ Bfr,
    float* __restrict__ energy)
{
    __shared__ float sbuf[512];
    const int blk = blockIdx.x, t = threadIdx.x;
    if (blk < 512) {
        const int a = blk;
        sbuf[t]       = Waw[(size_t)a * 512 + t];
        sbuf[t + 256] = Waw[(size_t)a * 512 + t + 256];
        __syncthreads();
        for (int cp = t; cp < Cn; cp += 256)
            Bfr[bfr_idx(a, cp)] = f2bf(Wec[(size_t)a * Cn + cp]);
        if (t < KKn) {
            float s = 0.f;
            #pragma unroll 8
            for (int k = 0; k < 512; ++k)
                s = fmaf(sbuf[k], Wac[k * KKn + t], s);
            Bfr[bfr_idx(a, Cn + t)] = f2bf(s);
        }
        for (int cp = CREAL + t; cp < CPAD; cp += 256)
            Bfr[bfr_idx(a, cp)] = 0;
    } else if (blk < 544) {
        const int b = blk - 512;
        sbuf[t] = (t < HIDn) ? hidden[b * HIDn + t] : 0.f;
        __syncthreads();
        for (int a = t; a < An; a += 256) {
            const float4* wp = (const float4*)(Wh + (size_t)a * HIDn);
            float s = bh[a] + bec[a];
            #pragma unroll 8
            for (int i = 0; i < HIDn / 4; ++i) {
                float4 w = wp[i];
                s = fmaf(sbuf[4 * i],     w.x, s);
                s = fmaf(sbuf[4 * i + 1], w.y, s);
                s = fmaf(sbuf[4 * i + 2], w.z, s);
                s = fmaf(sbuf[4 * i + 3], w.w, s);
            }
            query[b * An + a] = s;
        }
    } else {
        const int b = blk - 544;
        #pragma unroll
        for (int i = 0; i < 4; ++i)
            energy[b * HWn + i * 256 + t] = 0.f;
    }
}

// ---------------------------------------------------------------------------
// K_energy v11: ONE block per (b,hh); wave = 64m x 64n (nf=4).
//  - A staged ONCE per (b,hh) (v10 staged it twice, once per nh-block):
//    halves X traffic + barrier count; grid 512 = one clean round @2 blk/CU.
//  - Phase (~3K cy) >> load latency (~600-900 cy), so single-buffered va/bf
//    register sets (consume at phase start, reissue for +1/+2 in the same
//    phase) fully cover latency with NO ping-pong: acc64+af16+bf16+va4
//    ~122 regs < 128 cap -> no spill, 16 MFMA per barrier (was 8).
//  - VALU diet: loop split into pure-X part (ch 0..17, branch-free running
//    pointer) and mixed tail (ch 18..25, LDS LUT). R6 showed VALUBusy(21%)
//    > MfmaUtil(15%): addressing was beating the math.
//  - Issue va BEFORE bf: WRITEA's wait = counted vmcnt(4); MFMA waits only
//    phase-old L2 data. lgkm-only barrier (T4) + setprio (T5) kept.
//  - Single writer per (b,hh) -> energy plain store (no atomics).
__device__ __forceinline__ float fetchU(const float* __restrict__ Xb,
                                        const float* plane, const int* lut,
                                        int m, int row) {
    if (row < Cn) return Xb[(size_t)row * HWn + m];
    return plane[lut[row - Cn] + m];
}

__global__ __launch_bounds__(512, 4) void k_energy(
    const float* __restrict__ X,
    const float* __restrict__ asum,
    const float* __restrict__ Wv,
    const float* __restrict__ query,
    const unsigned short* __restrict__ Bfr,
    float* __restrict__ energy)
{
    __shared__ __align__(16) unsigned short As[2][64 * 40];   // 10,240B, stride 40
    __shared__ float plane[878];          // 814 im2col + 64 zero pad
    __shared__ int   lut[148];            // row-684 -> plane offset (or pad)
    __shared__ float qs[512];
    __shared__ float wvs[512];
    __shared__ float red[8][64];

    const int t = threadIdx.x;
    const int d = blockIdx.x;
    const int hh = d & 15, b = d >> 4;
    const int w = t >> 6, lane = t & 63;
    const int q = lane >> 4, r = lane & 15;
    const int mA = lane;                   // staging: m index; wave w -> k rows w*4..w*4+3

    const float* Xb = X + (size_t)b * Cn * HWn + hh * Wn;
    const unsigned short* Bp = Bfr + (size_t)(w * 4) * 26 * 512;

    // ---- prologue: plane(+zero pad) / lut / qs / wvs / chunk 0
    for (int i = t; i < 878; i += 512) {
        float v = 0.f;
        if (i < 814) {
            int di = i / 74, cc = i - di * 74;
            int h2 = hh + di - 5, w2 = cc - 5;
            if (h2 >= 0 && h2 < Hn && w2 >= 0 && w2 < Wn)
                v = asum[b * HWn + h2 * Wn + w2];
        }
        plane[i] = v;
    }
    if (t < 148) {
        int off = 814;                    // zero-pad region
        if (t < 121) { int di = t / 11; off = di * 74 + (t - di * 11); }
        lut[t] = off;
    }
    qs[t]  = query[b * An + t];
    wvs[t] = Wv[t];
    // stage A chunk 0: wave w loads rows w*4..w*4+3 (pure X)
    {
        const float* xp = Xb + (size_t)(w * 4) * HWn + mA;
        float v0 = xp[0];
        float v1 = xp[(size_t)1 * HWn];
        float v2 = xp[(size_t)2 * HWn];
        float v3 = xp[(size_t)3 * HWn];
        *(uint2*)&As[0][mA * 40 + w * 4] = make_uint2(cvt2(v0, v1), cvt2(v2, v3));
    }

    short8 bf[4], af[4];
    float va[4];

    // prologue issues (va FIRST, then bf — keeps WRITEA's wait counted):
    // va <- data(chunk 1) rows 32..63 (pure X); bf <- B(chunk 0)
    {
        const float* xp = Xb + (size_t)(32 + w * 4) * HWn + mA;
        va[0] = xp[0];
        va[1] = xp[(size_t)1 * HWn];
        va[2] = xp[(size_t)2 * HWn];
        va[3] = xp[(size_t)3 * HWn];
    }
    #pragma unroll
    for (int nf = 0; nf < 4; ++nf)
        bf[nf] = *(const short8*)(Bp + ((size_t)(nf * 26)) * 512 + lane * 8);
    __syncthreads();   // prologue: full drain once is fine

    floatx4 acc[4][4];
    #pragma unroll
    for (int mf = 0; mf < 4; ++mf)
        #pragma unroll
        for (int nf = 0; nf < 4; ++nf)
            acc[mf][nf] = (floatx4){0.f, 0.f, 0.f, 0.f};

#define READA(CUR) {                                                          \
    _Pragma("unroll")                                                         \
    for (int mf = 0; mf < 4; ++mf)                                            \
        af[mf] = *(const short8*)&As[CUR][(mf * 16 + r) * 40 + q * 8];        \
    }

#define WRITEA(CUR) {                                                         \
    *(uint2*)&As[CUR][mA * 40 + w * 4] =                                      \
        make_uint2(cvt2(va[0], va[1]), cvt2(va[2], va[3]));                   \
    }

#define MFMA16() {                                                            \
    __builtin_amdgcn_s_setprio(1);                                            \
    _Pragma("unroll")                                                         \
    for (int mf = 0; mf < 4; ++mf)                                            \
        _Pragma("unroll")                                                     \
        for (int nf = 0; nf < 4; ++nf)                                        \
            acc[mf][nf] = __builtin_amdgcn_mfma_f32_16x16x32_bf16(            \
                af[mf], bf[nf], acc[mf][nf], 0, 0, 0);                        \
    __builtin_amdgcn_s_setprio(0);                                            \
    }

#define ISSUE_BF(CC) {                                                        \
    _Pragma("unroll")                                                         \
    for (int nf = 0; nf < 4; ++nf)                                            \
        bf[nf] = *(const short8*)(Bp + ((size_t)(nf * 26 + (CC))) * 512       \
                                     + lane * 8);                             \
    }

#define LOOP_BARRIER() {                                                      \
    asm volatile("s_waitcnt lgkmcnt(0)" ::: "memory");                        \
    __builtin_amdgcn_sched_barrier(0);                                        \
    __builtin_amdgcn_s_barrier();                                             \
    __builtin_amdgcn_sched_barrier(0);                                        \
    }

    // pure-X running pointer for va issues (targets data chunk ch+2)
    const float* xva = Xb + (size_t)(64 + w * 4) * HWn + mA;
    const size_t chstep = (size_t)32 * HWn;

    // ---- loop 1: chunks 0..17 (va issues for data 2..19, all pure X)
    for (int ch = 0; ch < 18; ++ch) {
        const int cur = ch & 1;
        READA(cur);
        WRITEA(cur ^ 1);                  // va = data(ch+1), waits vmcnt(4)
        MFMA16();                         // bf = B(ch), phase-old L2 data
        // reissue: va <- data(ch+2) (branch-free), bf <- B(ch+1)
        va[0] = xva[0];
        va[1] = xva[(size_t)1 * HWn];
        va[2] = xva[(size_t)2 * HWn];
        va[3] = xva[(size_t)3 * HWn];
        xva += chstep;
        ISSUE_BF(ch + 1);
        LOOP_BARRIER();
    }

    // ---- loop 2: chunks 18..25 (mixed X / im2col tail via LDS LUT)
    for (int ch = 18; ch < NSTEP; ++ch) {
        const int cur = ch & 1;
        READA(cur);
        if (ch < NSTEP - 1) WRITEA(cur ^ 1);
        MFMA16();
        const int cva = (ch + 2 <= 25) ? (ch + 2) : 25;
        const int c0 = cva * 32 + w * 4;
        #pragma unroll
        for (int j = 0; j < 4; ++j)
            va[j] = fetchU(Xb, plane, lut, mA, c0 + j);
        const int cbf = (ch + 1 <= 25) ? (ch + 1) : 25;
        ISSUE_BF(cbf);
        LOOP_BARRIER();
    }

#undef READA
#undef WRITEA
#undef MFMA16
#undef ISSUE_BF
#undef LOOP_BARRIER

    // ---- epilogue: e[m] = sum_n Wv[n]*tanh(acc + query[n])
    float ep[16];
    #pragma unroll
    for (int i = 0; i < 16; ++i) ep[i] = 0.f;
    #pragma unroll
    for (int nf = 0; nf < 4; ++nf) {
        int nl = w * 64 + nf * 16 + r;
        float qv = qs[nl], wv = wvs[nl];
        #pragma unroll
        for (int mf = 0; mf < 4; ++mf)
            #pragma unroll
            for (int rg = 0; rg < 4; ++rg) {
                float x = acc[mf][nf][rg] + qv;
                float e2 = __expf(2.f * x);
                float th = 1.f - 2.f * __builtin_amdgcn_rcpf(e2 + 1.f);
                ep[mf * 4 + rg] += wv * th;
            }
    }
    // reduce over the 16 r-lanes (lane bits 0..3) via shfl_xor
    #pragma unroll
    for (int i = 0; i < 16; ++i) {
        #pragma unroll
        for (int msk = 1; msk <= 8; msk <<= 1)
            ep[i] += __shfl_xor(ep[i], msk, 64);
    }
    if (r == 0) {
        #pragma unroll
        for (int mf = 0; mf < 4; ++mf)
            #pragma unroll
            for (int rg = 0; rg < 4; ++rg)
                red[w][mf * 16 + q * 4 + rg] = ep[mf * 4 + rg];
    }
    __syncthreads();
    if (t < 64) {
        float s = 0.f;
        #pragma unroll
        for (int ww = 0; ww < 8; ++ww) s += red[ww][t];
        energy[b * HWn + hh * Wn + t] = s;   // single writer: plain store
    }
}

// ---------------------------------------------------------------------------
// K_softmax: one block per batch. alpha from energy once, written in-place
// over energy, plus alpha / alpha_sum_new outputs.
__global__ __launch_bounds__(256) void k_softmax(
    const float* __restrict__ mask,
    const float* __restrict__ asum,
    float* __restrict__ energy,     // in: energy, out: alpha
    float* __restrict__ out)
{
    __shared__ float rsm[8];
    const int b = blockIdx.x;
    const int t = threadIdx.x, lane = t & 63, wid = t >> 6;

    float e[4], ex[4];
    #pragma unroll
    for (int i = 0; i < 4; ++i) e[i] = energy[b * HWn + i * 256 + t];
    float m = fmaxf(fmaxf(e[0], e[1]), fmaxf(e[2], e[3]));
    for (int off = 32; off >= 1; off >>= 1) m = fmaxf(m, __shfl_down(m, off, 64));
    if (lane == 0) rsm[wid] = m;
    __syncthreads();
    if (t == 0)
        rsm[4] = fmaxf(fmaxf(rsm[0], rsm[1]), fmaxf(rsm[2], rsm[3]));
    __syncthreads();
    const float M = rsm[4];
    float s = 0.f;
    #pragma unroll
    for (int i = 0; i < 4; ++i) {
        ex[i] = expf(e[i] - M) * mask[b * HWn + i * 256 + t];
        s += ex[i];
    }
    for (int off = 32; off >= 1; off >>= 1) s += __shfl_down(s, off, 64);
    __syncthreads();
    if (lane == 0) rsm[wid] = s;
    __syncthreads();
    if (t == 0) rsm[5] = rsm[0] + rsm[1] + rsm[2] + rsm[3] + 1e-10f;
    __syncthreads();
    const float denom = rsm[5];
    #pragma unroll
    for (int i = 0; i < 4; ++i) {
        int p = i * 256 + t;
        float a = ex[i] / denom;
        energy[b * HWn + p] = a;
        out[OUT_ALPHA + b * HWn + p] = a;
        out[OUT_ASUM  + b * HWn + p] = a + asum[b * HWn + p];
    }
}

// ---------------------------------------------------------------------------
// K_ctx: pure context GEMV. Grid (171, 32); block caches alpha in LDS,
// wave wid handles channel bx*4+wid. Streams X once.
__global__ __launch_bounds__(256) void k_ctx(
    const float* __restrict__ X,
    const float* __restrict__ alpha,
    float* __restrict__ out)
{
    __shared__ float al[1024];
    const int bx = blockIdx.x, b = blockIdx.y;
    const int t = threadIdx.x, lane = t & 63, wid = t >> 6;

    #pragma unroll
    for (int i = 0; i < 4; ++i) al[i * 256 + t] = alpha[b * HWn + i * 256 + t];
    __syncthreads();

    const int c = bx * 4 + wid;
    const float* xp = X + ((size_t)(b * Cn + c)) * HWn;
    float s2 = 0.f;
    #pragma unroll
    for (int i = 0; i < 4; ++i) {
        int off = i * 256 + lane * 4;
        float4 x = *(const float4*)(xp + off);
        float4 a = *(const float4*)(al + off);
        s2 = fmaf(a.x, x.x, s2);
        s2 = fmaf(a.y, x.y, s2);
        s2 = fmaf(a.z, x.z, s2);
        s2 = fmaf(a.w, x.w, s2);
    }
    for (int off = 32; off >= 1; off >>= 1) s2 += __shfl_down(s2, off, 64);
    if (lane == 0) out[b * Cn + c] = s2;
}

// ---------------------------------------------------------------------------
extern "C" void kernel_launch(void* const* d_in, const int* in_sizes, int n_in,
                              void* d_out, int out_size, void* d_ws, size_t ws_size,
                              hipStream_t stream)
{
    const float* X      = (const float*)d_in[0];
    const float* hidden = (const float*)d_in[1];
    const float* asum   = (const float*)d_in[2];
    const float* mask   = (const float*)d_in[3];
    const float* Wh     = (const float*)d_in[4];
    const float* bh     = (const float*)d_in[5];
    const float* Wec    = (const float*)d_in[6];
    const float* bec    = (const float*)d_in[7];
    const float* Wac    = (const float*)d_in[8];
    const float* Waw    = (const float*)d_in[9];
    const float* Wv     = (const float*)d_in[10];
    (void)in_sizes; (void)n_in; (void)out_size; (void)ws_size;

    float* out = (float*)d_out;
    float* ws = (float*)d_ws;
    float* query  = ws;                                    // 16384 floats
    float* energy = ws + 16384;                            // 32768 (energy -> alpha)
    unsigned short* Bfr = (unsigned short*)(ws + 16384 + 32768); // 512*832 bf16

    k_prep    <<<dim3(576),      dim3(256), 0, stream>>>(hidden, Wh, bh, bec,
                                                         Wec, Wac, Waw, query, Bfr, energy);
    k_energy  <<<dim3(512),      dim3(512), 0, stream>>>(X, asum, Wv, query, Bfr, energy);
    k_softmax <<<dim3(32),       dim3(256), 0, stream>>>(mask, asum, energy, out);
    k_ctx     <<<dim3(171, 32),  dim3(256), 0, stream>>>(X, energy, out);
}

// Round 8
// 226.609 us; speedup vs baseline: 1.0604x; 1.0231x over previous
//
#include <hip/hip_runtime.h>
#include <hip/hip_bf16.h>
#include <math.h>

// Problem constants
#define Bn   32
#define Cn   684
#define Hn   16
#define Wn   64
#define HWn  1024
#define HIDn 256
#define An   512
#define KKn  121           // 11*11
#define CREAL 805          // 684 + 121
#define CPAD 832           // 26 chunks of 32
#define NSTEP 26

// Output layout (flat fp32): context [32,684] | alpha [32,1024] | alpha_sum_new [32,1024]
#define OUT_ALPHA 21888
#define OUT_ASUM  (21888 + 32768)

typedef short short8 __attribute__((ext_vector_type(8)));     // 8 bf16 = 4 VGPRs
typedef float floatx4 __attribute__((ext_vector_type(4)));    // MFMA acc

__device__ __forceinline__ unsigned short f2bf(float f) {
    union { float f; unsigned int i; } v; v.f = f;
    unsigned int i = v.i;
    return (unsigned short)((i + 0x7fffu + ((i >> 16) & 1u)) >> 16);
}
// f32 pair -> packed bf16 (RTNE), lowers to v_cvt_pk_bf16_f32 on gfx950
__device__ __forceinline__ unsigned int cvt2(float lo, float hi) {
    __hip_bfloat162 h = __float22bfloat162_rn(float2{lo, hi});
    union { __hip_bfloat162 h; unsigned int u; } cv; cv.h = h;
    return cv.u;
}

// Bfr fragment-order index: element (n, k) -> short index.
__device__ __forceinline__ size_t bfr_idx(int n, int k) {
    return ((((size_t)(n >> 4) * 26 + (k >> 5)) * 64
             + ((k >> 3) & 3) * 16 + (n & 15)) * 8) + (k & 7);
}

// ---------------------------------------------------------------------------
// K_prep: blocks 0..511 build Bfr row a (fragment-ordered); 512..543: query b;
// 544..575: init denom[b] = 1e-10 (energy no longer needs zeroing: k_energy
// plain-stores every element).
__global__ __launch_bounds__(256) void k_prep(
    const float* __restrict__ hidden,
    const float* __restrict__ Wh,
    const float* __restrict__ bh,
    const float* __restrict__ bec,
    const float* __restrict__ Wec,
    const float* __restrict__ Wac,
    const float* __restrict__ Waw,
    float* __restrict__ query,
    unsigned short* __restrict__ Bfr,
    float* __restrict__ denom)
{
    __shared__ float sbuf[512];
    const int blk = blockIdx.x, t = threadIdx.x;
    if (blk < 512) {
        const int a = blk;
        sbuf[t]       = Waw[(size_t)a * 512 + t];
        sbuf[t + 256] = Waw[(size_t)a * 512 + t + 256];
        __syncthreads();
        for (int cp = t; cp < Cn; cp += 256)
            Bfr[bfr_idx(a, cp)] = f2bf(Wec[(size_t)a * Cn + cp]);
        if (t < KKn) {
            float s = 0.f;
            #pragma unroll 8
            for (int k = 0; k < 512; ++k)
                s = fmaf(sbuf[k], Wac[k * KKn + t], s);
            Bfr[bfr_idx(a, Cn + t)] = f2bf(s);
        }
        for (int cp = CREAL + t; cp < CPAD; cp += 256)
            Bfr[bfr_idx(a, cp)] = 0;
    } else if (blk < 544) {
        const int b = blk - 512;
        sbuf[t] = (t < HIDn) ? hidden[b * HIDn + t] : 0.f;
        __syncthreads();
        for (int a = t; a < An; a += 256) {
            const float4* wp = (const float4*)(Wh + (size_t)a * HIDn);
            float s = bh[a] + bec[a];
            #pragma unroll 8
            for (int i = 0; i < HIDn / 4; ++i) {
                float4 w = wp[i];
                s = fmaf(sbuf[4 * i],     w.x, s);
                s = fmaf(sbuf[4 * i + 1], w.y, s);
                s = fmaf(sbuf[4 * i + 2], w.z, s);
                s = fmaf(sbuf[4 * i + 3], w.w, s);
            }
            query[b * An + a] = s;
        }
    } else {
        if (t == 0) denom[blk - 544] = 1e-10f;
    }
}

// ---------------------------------------------------------------------------
// K_energy v12: v11 loop (proven) + spill-free epilogue + fused exp/mask/denom.
//  - Epilogue restructured per-mf (ep4[4] live instead of ep[16]): kills the
//    14.4MB one-time scratch spill R7's WRITE_SIZE exposed (acc64+ep16 at the
//    128-reg cap).
//  - Softmax max-pass DELETED: |energy| <= ||Wv||_1 ~ 8 (tanh-bounded), so
//    exp(e) is safe in f32, and the reference's GLOBAL max-subtract (and bv)
//    cancels exactly in alpha = exp(e-M)m / sum(exp(e-M)m). Epilogue stores
//    expmask = exp(e)*mask into `energy` and atomicAdds the per-batch denom
//    (one atomic per (b,hh)). k_softmax kernel removed entirely.
__device__ __forceinline__ float fetchU(const float* __restrict__ Xb,
                                        const float* plane, const int* lut,
                                        int m, int row) {
    if (row < Cn) return Xb[(size_t)row * HWn + m];
    return plane[lut[row - Cn] + m];
}

__global__ __launch_bounds__(512, 4) void k_energy(
    const float* __restrict__ X,
    const float* __restrict__ asum,
    const float* __restrict__ Wv,
    const float* __restrict__ query,
    const unsigned short* __restrict__ Bfr,
    const float* __restrict__ mask,
    float* __restrict__ energy,      // out: expmask
    float* __restrict__ denom)
{
    __shared__ __align__(16) unsigned short As[2][64 * 40];   // 10,240B, stride 40
    __shared__ float plane[878];          // 814 im2col + 64 zero pad
    __shared__ int   lut[148];            // row-684 -> plane offset (or pad)
    __shared__ float qs[512];
    __shared__ float wvs[512];
    __shared__ float red[8][64];

    const int t = threadIdx.x;
    const int d = blockIdx.x;
    const int hh = d & 15, b = d >> 4;
    const int w = t >> 6, lane = t & 63;
    const int q = lane >> 4, r = lane & 15;
    const int mA = lane;                   // staging: m index; wave w -> k rows w*4..w*4+3

    const float* Xb = X + (size_t)b * Cn * HWn + hh * Wn;
    const unsigned short* Bp = Bfr + (size_t)(w * 4) * 26 * 512;

    // ---- prologue: plane(+zero pad) / lut / qs / wvs / chunk 0
    for (int i = t; i < 878; i += 512) {
        float v = 0.f;
        if (i < 814) {
            int di = i / 74, cc = i - di * 74;
            int h2 = hh + di - 5, w2 = cc - 5;
            if (h2 >= 0 && h2 < Hn && w2 >= 0 && w2 < Wn)
                v = asum[b * HWn + h2 * Wn + w2];
        }
        plane[i] = v;
    }
    if (t < 148) {
        int off = 814;                    // zero-pad region
        if (t < 121) { int di = t / 11; off = di * 74 + (t - di * 11); }
        lut[t] = off;
    }
    qs[t]  = query[b * An + t];
    wvs[t] = Wv[t];
    // stage A chunk 0: wave w loads rows w*4..w*4+3 (pure X)
    {
        const float* xp = Xb + (size_t)(w * 4) * HWn + mA;
        float v0 = xp[0];
        float v1 = xp[(size_t)1 * HWn];
        float v2 = xp[(size_t)2 * HWn];
        float v3 = xp[(size_t)3 * HWn];
        *(uint2*)&As[0][mA * 40 + w * 4] = make_uint2(cvt2(v0, v1), cvt2(v2, v3));
    }

    short8 bf[4], af[4];
    float va[4];

    // prologue issues (va FIRST, then bf — keeps WRITEA's wait counted):
    {
        const float* xp = Xb + (size_t)(32 + w * 4) * HWn + mA;
        va[0] = xp[0];
        va[1] = xp[(size_t)1 * HWn];
        va[2] = xp[(size_t)2 * HWn];
        va[3] = xp[(size_t)3 * HWn];
    }
    #pragma unroll
    for (int nf = 0; nf < 4; ++nf)
        bf[nf] = *(const short8*)(Bp + ((size_t)(nf * 26)) * 512 + lane * 8);
    __syncthreads();   // prologue: full drain once is fine

    floatx4 acc[4][4];
    #pragma unroll
    for (int mf = 0; mf < 4; ++mf)
        #pragma unroll
        for (int nf = 0; nf < 4; ++nf)
            acc[mf][nf] = (floatx4){0.f, 0.f, 0.f, 0.f};

#define READA(CUR) {                                                          \
    _Pragma("unroll")                                                         \
    for (int mf = 0; mf < 4; ++mf)                                            \
        af[mf] = *(const short8*)&As[CUR][(mf * 16 + r) * 40 + q * 8];        \
    }

#define WRITEA(CUR) {                                                         \
    *(uint2*)&As[CUR][mA * 40 + w * 4] =                                      \
        make_uint2(cvt2(va[0], va[1]), cvt2(va[2], va[3]));                   \
    }

#define MFMA16() {                                                            \
    __builtin_amdgcn_s_setprio(1);                                            \
    _Pragma("unroll")                                                         \
    for (int mf = 0; mf < 4; ++mf)                                            \
        _Pragma("unroll")                                                     \
        for (int nf = 0; nf < 4; ++nf)                                        \
            acc[mf][nf] = __builtin_amdgcn_mfma_f32_16x16x32_bf16(            \
                af[mf], bf[nf], acc[mf][nf], 0, 0, 0);                        \
    __builtin_amdgcn_s_setprio(0);                                            \
    }

#define ISSUE_BF(CC) {                                                        \
    _Pragma("unroll")                                                         \
    for (int nf = 0; nf < 4; ++nf)                                            \
        bf[nf] = *(const short8*)(Bp + ((size_t)(nf * 26 + (CC))) * 512       \
                                     + lane * 8);                             \
    }

#define LOOP_BARRIER() {                                                      \
    asm volatile("s_waitcnt lgkmcnt(0)" ::: "memory");                        \
    __builtin_amdgcn_sched_barrier(0);                                        \
    __builtin_amdgcn_s_barrier();                                             \
    __builtin_amdgcn_sched_barrier(0);                                        \
    }

    // pure-X running pointer for va issues (targets data chunk ch+2)
    const float* xva = Xb + (size_t)(64 + w * 4) * HWn + mA;
    const size_t chstep = (size_t)32 * HWn;

    // ---- loop 1: chunks 0..17 (va issues for data 2..19, all pure X)
    for (int ch = 0; ch < 18; ++ch) {
        const int cur = ch & 1;
        READA(cur);
        WRITEA(cur ^ 1);                  // va = data(ch+1), waits counted vmcnt
        MFMA16();                         // bf = B(ch), phase-old L2 data
        va[0] = xva[0];
        va[1] = xva[(size_t)1 * HWn];
        va[2] = xva[(size_t)2 * HWn];
        va[3] = xva[(size_t)3 * HWn];
        xva += chstep;
        ISSUE_BF(ch + 1);
        LOOP_BARRIER();
    }

    // ---- loop 2: chunks 18..25 (mixed X / im2col tail via LDS LUT)
    for (int ch = 18; ch < NSTEP; ++ch) {
        const int cur = ch & 1;
        READA(cur);
        if (ch < NSTEP - 1) WRITEA(cur ^ 1);
        MFMA16();
        const int cva = (ch + 2 <= 25) ? (ch + 2) : 25;
        const int c0 = cva * 32 + w * 4;
        #pragma unroll
        for (int j = 0; j < 4; ++j)
            va[j] = fetchU(Xb, plane, lut, mA, c0 + j);
        const int cbf = (ch + 1 <= 25) ? (ch + 1) : 25;
        ISSUE_BF(cbf);
        LOOP_BARRIER();
    }

#undef READA
#undef WRITEA
#undef MFMA16
#undef ISSUE_BF
#undef LOOP_BARRIER

    // ---- epilogue v12: per-mf reduction (ep4[4] live, not ep[16] -> no spill)
    #pragma unroll
    for (int mf = 0; mf < 4; ++mf) {
        float ep4[4];
        #pragma unroll
        for (int rg = 0; rg < 4; ++rg) ep4[rg] = 0.f;
        #pragma unroll
        for (int nf = 0; nf < 4; ++nf) {
            int nl = w * 64 + nf * 16 + r;
            float qv = qs[nl], wv = wvs[nl];
            #pragma unroll
            for (int rg = 0; rg < 4; ++rg) {
                float x = acc[mf][nf][rg] + qv;
                float e2 = __expf(2.f * x);
                float th = 1.f - 2.f * __builtin_amdgcn_rcpf(e2 + 1.f);
                ep4[rg] = fmaf(wv, th, ep4[rg]);
            }
        }
        // reduce over the 16 r-lanes (lane bits 0..3)
        #pragma unroll
        for (int rg = 0; rg < 4; ++rg) {
            #pragma unroll
            for (int msk = 1; msk <= 8; msk <<= 1)
                ep4[rg] += __shfl_xor(ep4[rg], msk, 64);
        }
        if (r == 0) {
            #pragma unroll
            for (int rg = 0; rg < 4; ++rg)
                red[w][mf * 16 + q * 4 + rg] = ep4[rg];
        }
    }
    __syncthreads();
    if (t < 64) {
        float s = 0.f;
        #pragma unroll
        for (int ww = 0; ww < 8; ++ww) s += red[ww][t];
        // fused: expmask = exp(e) * mask  (global max-subtract & bv cancel
        // exactly in alpha; |e| <= ~8 so exp is f32-safe)
        float em = __expf(s) * mask[b * HWn + hh * Wn + t];
        energy[b * HWn + hh * Wn + t] = em;
        // per-batch denominator: wave-reduce then one atomic per (b,hh)
        float ds = em;
        #pragma unroll
        for (int off = 32; off >= 1; off >>= 1)
            ds += __shfl_down(ds, off, 64);
        if (t == 0) atomicAdd(&denom[b], ds);
    }
}

// ---------------------------------------------------------------------------
// K_ctx v3: context GEMV + inline alpha = expmask/denom. Grid (171, 32).
// Block caches alpha in LDS; wave wid handles channel bx*4+wid; bx==0 also
// writes alpha / alpha_sum_new outputs.
__global__ __launch_bounds__(256) void k_ctx(
    const float* __restrict__ X,
    const float* __restrict__ expmask,
    const float* __restrict__ denom,
    const float* __restrict__ asum,
    float* __restrict__ out)
{
    __shared__ float al[1024];
    const int bx = blockIdx.x, b = blockIdx.y;
    const int t = threadIdx.x, lane = t & 63, wid = t >> 6;

    const float rd = 1.f / denom[b];
    #pragma unroll
    for (int i = 0; i < 4; ++i)
        al[i * 256 + t] = expmask[b * HWn + i * 256 + t] * rd;
    __syncthreads();

    const int c = bx * 4 + wid;
    const float* xp = X + ((size_t)(b * Cn + c)) * HWn;
    float s2 = 0.f;
    #pragma unroll
    for (int i = 0; i < 4; ++i) {
        int off = i * 256 + lane * 4;
        float4 x = *(const float4*)(xp + off);
        float4 a = *(const float4*)(al + off);
        s2 = fmaf(a.x, x.x, s2);
        s2 = fmaf(a.y, x.y, s2);
        s2 = fmaf(a.z, x.z, s2);
        s2 = fmaf(a.w, x.w, s2);
    }
    for (int off = 32; off >= 1; off >>= 1) s2 += __shfl_down(s2, off, 64);
    if (lane == 0) out[b * Cn + c] = s2;

    if (bx == 0) {
        #pragma unroll
        for (int i = 0; i < 4; ++i) {
            int p = i * 256 + t;
            float a = al[p];
            out[OUT_ALPHA + b * HWn + p] = a;
            out[OUT_ASUM  + b * HWn + p] = a + asum[b * HWn + p];
        }
    }
}

// ---------------------------------------------------------------------------
extern "C" void kernel_launch(void* const* d_in, const int* in_sizes, int n_in,
                              void* d_out, int out_size, void* d_ws, size_t ws_size,
                              hipStream_t stream)
{
    const float* X      = (const float*)d_in[0];
    const float* hidden = (const float*)d_in[1];
    const float* asum   = (const float*)d_in[2];
    const float* mask   = (const float*)d_in[3];
    const float* Wh     = (const float*)d_in[4];
    const float* bh     = (const float*)d_in[5];
    const float* Wec    = (const float*)d_in[6];
    const float* bec    = (const float*)d_in[7];
    const float* Wac    = (const float*)d_in[8];
    const float* Waw    = (const float*)d_in[9];
    const float* Wv     = (const float*)d_in[10];
    (void)in_sizes; (void)n_in; (void)out_size; (void)ws_size;

    float* out = (float*)d_out;
    float* ws = (float*)d_ws;
    float* query  = ws;                                    // 16384 floats
    float* energy = ws + 16384;                            // 32768 (expmask)
    float* denom  = ws + 16384 + 32768;                    // 32 floats (+pad 64)
    unsigned short* Bfr = (unsigned short*)(ws + 16384 + 32768 + 64); // 512*832 bf16

    k_prep   <<<dim3(576),      dim3(256), 0, stream>>>(hidden, Wh, bh, bec,
                                                        Wec, Wac, Waw, query, Bfr, denom);
    k_energy <<<dim3(512),      dim3(512), 0, stream>>>(X, asum, Wv, query, Bfr,
                                                        mask, energy, denom);
    k_ctx    <<<dim3(171, 32),  dim3(256), 0, stream>>>(X, energy, denom, asum, out);
}

// Round 10
// 225.908 us; speedup vs baseline: 1.0637x; 1.0031x over previous
//
#include <hip/hip_runtime.h>
#include <hip/hip_bf16.h>
#include <math.h>

// Problem constants
#define Bn   32
#define Cn   684
#define Hn   16
#define Wn   64
#define HWn  1024
#define HIDn 256
#define An   512
#define KKn  121           // 11*11
#define CREAL 805          // 684 + 121
#define CPAD 832           // 26 chunks of 32
#define NSTEP 26

// Output layout (flat fp32): context [32,684] | alpha [32,1024] | alpha_sum_new [32,1024]
#define OUT_ALPHA 21888
#define OUT_ASUM  (21888 + 32768)

typedef short short8 __attribute__((ext_vector_type(8)));     // 8 bf16 = 4 VGPRs
typedef float floatx4 __attribute__((ext_vector_type(4)));    // MFMA acc

__device__ __forceinline__ unsigned short f2bf(float f) {
    union { float f; unsigned int i; } v; v.f = f;
    unsigned int i = v.i;
    return (unsigned short)((i + 0x7fffu + ((i >> 16) & 1u)) >> 16);
}
// f32 pair -> packed bf16 (RTNE), lowers to v_cvt_pk_bf16_f32 on gfx950
__device__ __forceinline__ unsigned int cvt2(float lo, float hi) {
    __hip_bfloat162 h = __float22bfloat162_rn(float2{lo, hi});
    union { __hip_bfloat162 h; unsigned int u; } cv; cv.h = h;
    return cv.u;
}

// Bfr fragment-order index: element (n, k) -> short index.
__device__ __forceinline__ size_t bfr_idx(int n, int k) {
    return ((((size_t)(n >> 4) * 26 + (k >> 5)) * 64
             + ((k >> 3) & 3) * 16 + (n & 15)) * 8) + (k & 7);
}

// ---------------------------------------------------------------------------
// K_prep (R8-proven): blocks 0..511 build Bfr row a; 512..543: query b;
// 544..575: init denom[b] = 1e-10.
__global__ __launch_bounds__(256) void k_prep(
    const float* __restrict__ hidden,
    const float* __restrict__ Wh,
    const float* __restrict__ bh,
    const float* __restrict__ bec,
    const float* __restrict__ Wec,
    const float* __restrict__ Wac,
    const float* __restrict__ Waw,
    float* __restrict__ query,
    unsigned short* __restrict__ Bfr,
    float* __restrict__ denom)
{
    __shared__ float sbuf[512];
    const int blk = blockIdx.x, t = threadIdx.x;
    if (blk < 512) {
        const int a = blk;
        sbuf[t]       = Waw[(size_t)a * 512 + t];
        sbuf[t + 256] = Waw[(size_t)a * 512 + t + 256];
        __syncthreads();
        for (int cp = t; cp < Cn; cp += 256)
            Bfr[bfr_idx(a, cp)] = f2bf(Wec[(size_t)a * Cn + cp]);
        if (t < KKn) {
            float s = 0.f;
            #pragma unroll 8
            for (int k = 0; k < 512; ++k)
                s = fmaf(sbuf[k], Wac[k * KKn + t], s);
            Bfr[bfr_idx(a, Cn + t)] = f2bf(s);
        }
        for (int cp = CREAL + t; cp < CPAD; cp += 256)
            Bfr[bfr_idx(a, cp)] = 0;
    } else if (blk < 544) {
        const int b = blk - 512;
        sbuf[t] = (t < HIDn) ? hidden[b * HIDn + t] : 0.f;
        __syncthreads();
        for (int a = t; a < An; a += 256) {
            const float4* wp = (const float4*)(Wh + (size_t)a * HIDn);
            float s = bh[a] + bec[a];
            #pragma unroll 8
            for (int i = 0; i < HIDn / 4; ++i) {
                float4 w = wp[i];
                s = fmaf(sbuf[4 * i],     w.x, s);
                s = fmaf(sbuf[4 * i + 1], w.y, s);
                s = fmaf(sbuf[4 * i + 2], w.z, s);
                s = fmaf(sbuf[4 * i + 3], w.w, s);
            }
            query[b * An + a] = s;
        }
    } else {
        if (t == 0) denom[blk - 544] = 1e-10f;
    }
}

// ---------------------------------------------------------------------------
// K_energy v12 (R8-proven, verbatim): v11 loop + spill-free epilogue +
// fused exp/mask/denom. R9's planeG variant reverted: its 1.8MB workspace
// region exceeded the proven footprint and is the prime suspect for the
// container fault. The residual 8.3MB tail spill (~2-3us) is accepted.
__device__ __forceinline__ float fetchU(const float* __restrict__ Xb,
                                        const float* plane, const int* lut,
                                        int m, int row) {
    if (row < Cn) return Xb[(size_t)row * HWn + m];
    return plane[lut[row - Cn] + m];
}

__global__ __launch_bounds__(512, 4) void k_energy(
    const float* __restrict__ X,
    const float* __restrict__ asum,
    const float* __restrict__ Wv,
    const float* __restrict__ query,
    const unsigned short* __restrict__ Bfr,
    const float* __restrict__ mask,
    float* __restrict__ energy,      // out: expmask
    float* __restrict__ denom)
{
    __shared__ __align__(16) unsigned short As[2][64 * 40];   // 10,240B, stride 40
    __shared__ float plane[878];          // 814 im2col + 64 zero pad
    __shared__ int   lut[148];            // row-684 -> plane offset (or pad)
    __shared__ float qs[512];
    __shared__ float wvs[512];
    __shared__ float red[8][64];

    const int t = threadIdx.x;
    const int d = blockIdx.x;
    const int hh = d & 15, b = d >> 4;
    const int w = t >> 6, lane = t & 63;
    const int q = lane >> 4, r = lane & 15;
    const int mA = lane;                   // staging: m index; wave w -> k rows w*4..w*4+3

    const float* Xb = X + (size_t)b * Cn * HWn + hh * Wn;
    const unsigned short* Bp = Bfr + (size_t)(w * 4) * 26 * 512;

    // ---- prologue: plane(+zero pad) / lut / qs / wvs / chunk 0
    for (int i = t; i < 878; i += 512) {
        float v = 0.f;
        if (i < 814) {
            int di = i / 74, cc = i - di * 74;
            int h2 = hh + di - 5, w2 = cc - 5;
            if (h2 >= 0 && h2 < Hn && w2 >= 0 && w2 < Wn)
                v = asum[b * HWn + h2 * Wn + w2];
        }
        plane[i] = v;
    }
    if (t < 148) {
        int off = 814;                    // zero-pad region
        if (t < 121) { int di = t / 11; off = di * 74 + (t - di * 11); }
        lut[t] = off;
    }
    qs[t]  = query[b * An + t];
    wvs[t] = Wv[t];
    // stage A chunk 0: wave w loads rows w*4..w*4+3 (pure X)
    {
        const float* xp = Xb + (size_t)(w * 4) * HWn + mA;
        float v0 = xp[0];
        float v1 = xp[(size_t)1 * HWn];
        float v2 = xp[(size_t)2 * HWn];
        float v3 = xp[(size_t)3 * HWn];
        *(uint2*)&As[0][mA * 40 + w * 4] = make_uint2(cvt2(v0, v1), cvt2(v2, v3));
    }

    short8 bf[4], af[4];
    float va[4];

    // prologue issues (va FIRST, then bf — keeps WRITEA's wait counted):
    {
        const float* xp = Xb + (size_t)(32 + w * 4) * HWn + mA;
        va[0] = xp[0];
        va[1] = xp[(size_t)1 * HWn];
        va[2] = xp[(size_t)2 * HWn];
        va[3] = xp[(size_t)3 * HWn];
    }
    #pragma unroll
    for (int nf = 0; nf < 4; ++nf)
        bf[nf] = *(const short8*)(Bp + ((size_t)(nf * 26)) * 512 + lane * 8);
    __syncthreads();   // prologue: full drain once is fine

    floatx4 acc[4][4];
    #pragma unroll
    for (int mf = 0; mf < 4; ++mf)
        #pragma unroll
        for (int nf = 0; nf < 4; ++nf)
            acc[mf][nf] = (floatx4){0.f, 0.f, 0.f, 0.f};

#define READA(CUR) {                                                          \
    _Pragma("unroll")                                                         \
    for (int mf = 0; mf < 4; ++mf)                                            \
        af[mf] = *(const short8*)&As[CUR][(mf * 16 + r) * 40 + q * 8];        \
    }

#define WRITEA(CUR) {                                                         \
    *(uint2*)&As[CUR][mA * 40 + w * 4] =                                      \
        make_uint2(cvt2(va[0], va[1]), cvt2(va[2], va[3]));                   \
    }

#define MFMA16() {                                                            \
    __builtin_amdgcn_s_setprio(1);                                            \
    _Pragma("unroll")                                                         \
    for (int mf = 0; mf < 4; ++mf)                                            \
        _Pragma("unroll")                                                     \
        for (int nf = 0; nf < 4; ++nf)                                        \
            acc[mf][nf] = __builtin_amdgcn_mfma_f32_16x16x32_bf16(            \
                af[mf], bf[nf], acc[mf][nf], 0, 0, 0);                        \
    __builtin_amdgcn_s_setprio(0);                                            \
    }

#define ISSUE_BF(CC) {                                                        \
    _Pragma("unroll")                                                         \
    for (int nf = 0; nf < 4; ++nf)                                            \
        bf[nf] = *(const short8*)(Bp + ((size_t)(nf * 26 + (CC))) * 512       \
                                     + lane * 8);                             \
    }

#define LOOP_BARRIER() {                                                      \
    asm volatile("s_waitcnt lgkmcnt(0)" ::: "memory");                        \
    __builtin_amdgcn_sched_barrier(0);                                        \
    __builtin_amdgcn_s_barrier();                                             \
    __builtin_amdgcn_sched_barrier(0);                                        \
    }

    // pure-X running pointer for va issues (targets data chunk ch+2)
    const float* xva = Xb + (size_t)(64 + w * 4) * HWn + mA;
    const size_t chstep = (size_t)32 * HWn;

    // ---- loop 1: chunks 0..17 (va issues for data 2..19, all pure X)
    for (int ch = 0; ch < 18; ++ch) {
        const int cur = ch & 1;
        READA(cur);
        WRITEA(cur ^ 1);                  // va = data(ch+1), waits counted vmcnt
        MFMA16();                         // bf = B(ch), phase-old L2 data
        va[0] = xva[0];
        va[1] = xva[(size_t)1 * HWn];
        va[2] = xva[(size_t)2 * HWn];
        va[3] = xva[(size_t)3 * HWn];
        xva += chstep;
        ISSUE_BF(ch + 1);
        LOOP_BARRIER();
    }

    // ---- loop 2: chunks 18..25 (mixed X / im2col tail via LDS LUT)
    for (int ch = 18; ch < NSTEP; ++ch) {
        const int cur = ch & 1;
        READA(cur);
        if (ch < NSTEP - 1) WRITEA(cur ^ 1);
        MFMA16();
        const int cva = (ch + 2 <= 25) ? (ch + 2) : 25;
        const int c0 = cva * 32 + w * 4;
        #pragma unroll
        for (int j = 0; j < 4; ++j)
            va[j] = fetchU(Xb, plane, lut, mA, c0 + j);
        const int cbf = (ch + 1 <= 25) ? (ch + 1) : 25;
        ISSUE_BF(cbf);
        LOOP_BARRIER();
    }

#undef READA
#undef WRITEA
#undef MFMA16
#undef ISSUE_BF
#undef LOOP_BARRIER

    // ---- epilogue: per-mf reduction (spill-free), fused exp/mask/denom
    #pragma unroll
    for (int mf = 0; mf < 4; ++mf) {
        float ep4[4];
        #pragma unroll
        for (int rg = 0; rg < 4; ++rg) ep4[rg] = 0.f;
        #pragma unroll
        for (int nf = 0; nf < 4; ++nf) {
            int nl = w * 64 + nf * 16 + r;
            float qv = qs[nl], wv = wvs[nl];
            #pragma unroll
            for (int rg = 0; rg < 4; ++rg) {
                float x = acc[mf][nf][rg] + qv;
                float e2 = __expf(2.f * x);
                float th = 1.f - 2.f * __builtin_amdgcn_rcpf(e2 + 1.f);
                ep4[rg] = fmaf(wv, th, ep4[rg]);
            }
        }
        #pragma unroll
        for (int rg = 0; rg < 4; ++rg) {
            #pragma unroll
            for (int msk = 1; msk <= 8; msk <<= 1)
                ep4[rg] += __shfl_xor(ep4[rg], msk, 64);
        }
        if (r == 0) {
            #pragma unroll
            for (int rg = 0; rg < 4; ++rg)
                red[w][mf * 16 + q * 4 + rg] = ep4[rg];
        }
    }
    __syncthreads();
    if (t < 64) {
        float s = 0.f;
        #pragma unroll
        for (int ww = 0; ww < 8; ++ww) s += red[ww][t];
        // expmask = exp(e)*mask (global max-subtract & bv cancel in alpha)
        float em = __expf(s) * mask[b * HWn + hh * Wn + t];
        energy[b * HWn + hh * Wn + t] = em;
        float ds = em;
        #pragma unroll
        for (int off = 32; off >= 1; off >>= 1)
            ds += __shfl_down(ds, off, 64);
        if (t == 0) atomicAdd(&denom[b], ds);
    }
}

// ---------------------------------------------------------------------------
// K_ctx v4: 16 channels/block (4 per wave, 4 independent acc chains = 16
// float4 X-loads in flight/wave vs v3's 4) + alpha staged once per 16
// channels (4x amortization). Grid (43, 32); tail channels clamped.
__global__ __launch_bounds__(256) void k_ctx(
    const float* __restrict__ X,
    const float* __restrict__ expmask,
    const float* __restrict__ denom,
    const float* __restrict__ asum,
    float* __restrict__ out)
{
    __shared__ float al[1024];
    const int bx = blockIdx.x, b = blockIdx.y;
    const int t = threadIdx.x, lane = t & 63, wid = t >> 6;

    const float rd = 1.f / denom[b];
    #pragma unroll
    for (int i = 0; i < 4; ++i)
        al[i * 256 + t] = expmask[b * HWn + i * 256 + t] * rd;
    __syncthreads();

    const int c0 = bx * 16 + wid * 4;
    const float* xpc[4];
    #pragma unroll
    for (int cc = 0; cc < 4; ++cc) {
        int c = c0 + cc; if (c >= Cn) c = Cn - 1;    // clamp (dup ch, no OOB)
        xpc[cc] = X + ((size_t)(b * Cn + c)) * HWn;
    }
    float s0 = 0.f, s1 = 0.f, s2 = 0.f, s3 = 0.f;
    #pragma unroll
    for (int i = 0; i < 4; ++i) {
        const int off = i * 256 + lane * 4;
        float4 a = *(const float4*)(al + off);
        float4 x0 = *(const float4*)(xpc[0] + off);
        float4 x1 = *(const float4*)(xpc[1] + off);
        float4 x2 = *(const float4*)(xpc[2] + off);
        float4 x3 = *(const float4*)(xpc[3] + off);
        s0 = fmaf(a.x, x0.x, s0); s0 = fmaf(a.y, x0.y, s0);
        s0 = fmaf(a.z, x0.z, s0); s0 = fmaf(a.w, x0.w, s0);
        s1 = fmaf(a.x, x1.x, s1); s1 = fmaf(a.y, x1.y, s1);
        s1 = fmaf(a.z, x1.z, s1); s1 = fmaf(a.w, x1.w, s1);
        s2 = fmaf(a.x, x2.x, s2); s2 = fmaf(a.y, x2.y, s2);
        s2 = fmaf(a.z, x2.z, s2); s2 = fmaf(a.w, x2.w, s2);
        s3 = fmaf(a.x, x3.x, s3); s3 = fmaf(a.y, x3.y, s3);
        s3 = fmaf(a.z, x3.z, s3); s3 = fmaf(a.w, x3.w, s3);
    }
    float sv[4] = {s0, s1, s2, s3};
    #pragma unroll
    for (int cc = 0; cc < 4; ++cc) {
        float s = sv[cc];
        #pragma unroll
        for (int off = 32; off >= 1; off >>= 1)
            s += __shfl_down(s, off, 64);
        if (lane == 0 && c0 + cc < Cn) out[b * Cn + c0 + cc] = s;
    }

    if (bx == 0) {
        #pragma unroll
        for (int i = 0; i < 4; ++i) {
            int p = i * 256 + t;
            float a = al[p];
            out[OUT_ALPHA + b * HWn + p] = a;
            out[OUT_ASUM  + b * HWn + p] = a + asum[b * HWn + p];
        }
    }
}

// ---------------------------------------------------------------------------
extern "C" void kernel_launch(void* const* d_in, const int* in_sizes, int n_in,
                              void* d_out, int out_size, void* d_ws, size_t ws_size,
                              hipStream_t stream)
{
    const float* X      = (const float*)d_in[0];
    const float* hidden = (const float*)d_in[1];
    const float* asum   = (const float*)d_in[2];
    const float* mask   = (const float*)d_in[3];
    const float* Wh     = (const float*)d_in[4];
    const float* bh     = (const float*)d_in[5];
    const float* Wec    = (const float*)d_in[6];
    const float* bec    = (const float*)d_in[7];
    const float* Wac    = (const float*)d_in[8];
    const float* Waw    = (const float*)d_in[9];
    const float* Wv     = (const float*)d_in[10];
    (void)in_sizes; (void)n_in; (void)out_size; (void)ws_size;

    float* out = (float*)d_out;
    float* ws = (float*)d_ws;
    float* query  = ws;                                    // 16384 floats
    float* energy = ws + 16384;                            // 32768 (expmask)
    float* denom  = ws + 16384 + 32768;                    // 32 floats (+pad 64)
    unsigned short* Bfr = (unsigned short*)(ws + 16384 + 32768 + 64); // 512*832 bf16

    k_prep   <<<dim3(576),      dim3(256), 0, stream>>>(hidden, Wh, bh, bec,
                                                        Wec, Wac, Waw, query, Bfr, denom);
    k_energy <<<dim3(512),      dim3(512), 0, stream>>>(X, asum, Wv, query, Bfr,
                                                        mask, energy, denom);
    k_ctx    <<<dim3(43, 32),   dim3(256), 0, stream>>>(X, energy, denom, asum, out);
}

// Round 11
// 221.272 us; speedup vs baseline: 1.0860x; 1.0210x over previous
//
#include <hip/hip_runtime.h>
#include <hip/hip_bf16.h>
#include <math.h>

// Problem constants
#define Bn   32
#define Cn   684
#define Hn   16
#define Wn   64
#define HWn  1024
#define HIDn 256
#define An   512
#define KKn  121           // 11*11
#define CREAL 805          // 684 + 121
#define CPAD 832           // 26 chunks of 32
#define NSTEP 26

// Output layout (flat fp32): context [32,684] | alpha [32,1024] | alpha_sum_new [32,1024]
#define OUT_ALPHA 21888
#define OUT_ASUM  (21888 + 32768)

typedef short short8 __attribute__((ext_vector_type(8)));     // 8 bf16 = 4 VGPRs
typedef float floatx4 __attribute__((ext_vector_type(4)));    // MFMA acc

__device__ __forceinline__ unsigned short f2bf(float f) {
    union { float f; unsigned int i; } v; v.f = f;
    unsigned int i = v.i;
    return (unsigned short)((i + 0x7fffu + ((i >> 16) & 1u)) >> 16);
}
// f32 pair -> packed bf16 (RTNE), lowers to v_cvt_pk_bf16_f32 on gfx950
__device__ __forceinline__ unsigned int cvt2(float lo, float hi) {
    __hip_bfloat162 h = __float22bfloat162_rn(float2{lo, hi});
    union { __hip_bfloat162 h; unsigned int u; } cv; cv.h = h;
    return cv.u;
}

// Bfr fragment-order index: element (n, k) -> short index.
__device__ __forceinline__ size_t bfr_idx(int n, int k) {
    return ((((size_t)(n >> 4) * 26 + (k >> 5)) * 64
             + ((k >> 3) & 3) * 16 + (n & 15)) * 8) + (k & 7);
}

// ---------------------------------------------------------------------------
// K_prep (R8-proven): blocks 0..511 build Bfr row a; 512..543: query b;
// 544..575: init denom[b] = 1e-10.
__global__ __launch_bounds__(256) void k_prep(
    const float* __restrict__ hidden,
    const float* __restrict__ Wh,
    const float* __restrict__ bh,
    const float* __restrict__ bec,
    const float* __restrict__ Wec,
    const float* __restrict__ Wac,
    const float* __restrict__ Waw,
    float* __restrict__ query,
    unsigned short* __restrict__ Bfr,
    float* __restrict__ denom)
{
    __shared__ float sbuf[512];
    const int blk = blockIdx.x, t = threadIdx.x;
    if (blk < 512) {
        const int a = blk;
        sbuf[t]       = Waw[(size_t)a * 512 + t];
        sbuf[t + 256] = Waw[(size_t)a * 512 + t + 256];
        __syncthreads();
        for (int cp = t; cp < Cn; cp += 256)
            Bfr[bfr_idx(a, cp)] = f2bf(Wec[(size_t)a * Cn + cp]);
        if (t < KKn) {
            float s = 0.f;
            #pragma unroll 8
            for (int k = 0; k < 512; ++k)
                s = fmaf(sbuf[k], Wac[k * KKn + t], s);
            Bfr[bfr_idx(a, Cn + t)] = f2bf(s);
        }
        for (int cp = CREAL + t; cp < CPAD; cp += 256)
            Bfr[bfr_idx(a, cp)] = 0;
    } else if (blk < 544) {
        const int b = blk - 512;
        sbuf[t] = (t < HIDn) ? hidden[b * HIDn + t] : 0.f;
        __syncthreads();
        for (int a = t; a < An; a += 256) {
            const float4* wp = (const float4*)(Wh + (size_t)a * HIDn);
            float s = bh[a] + bec[a];
            #pragma unroll 8
            for (int i = 0; i < HIDn / 4; ++i) {
                float4 w = wp[i];
                s = fmaf(sbuf[4 * i],     w.x, s);
                s = fmaf(sbuf[4 * i + 1], w.y, s);
                s = fmaf(sbuf[4 * i + 2], w.z, s);
                s = fmaf(sbuf[4 * i + 3], w.w, s);
            }
            query[b * An + a] = s;
        }
    } else {
        if (t == 0) denom[blk - 544] = 1e-10f;
    }
}

// ---------------------------------------------------------------------------
// K_energy v14: super-chunk K=64 (barrier per 2 chunks), stride-42 LDS,
// bijective XCD swizzle.
//  - 4 chunk-buffers: super s reads bufs {2(s&1), 2(s&1)+1} (chunks 2s,2s+1),
//    writes bufs ^2 (chunks 2s+2,2s+3) -> disjoint -> ONE barrier per super.
//    13 barriers (was 26), 32 MFMA/barrier: amortizes the s_barrier convoy
//    that left 80% of chunk-slot cycles idle (5.5K cy/chunk vs 1.2K issue).
//  - Wave stages 8 k-rows -> one ds_write_b128. Stride 42 shorts (84B):
//    write banks 21*m mod 32 (2-way, free) vs stride-40's 8-way; reads <=2-way.
//  - bf re-issued mid-super (Bfr L2-resident, ~200cy, covered by ds+va issue).
//  - XCD swizzle: xcd=d&7, b=xcd*4+(idx>>4) -> all 16 hh-blocks of a batch
//    share one XCD's L2 (X[b] slice = 2.8MB).
//  - Regs: va8+af16+bf16+acc64+addr ~124 < 128 (2 blk/CU preserved).
__device__ __forceinline__ float fetchU(const float* __restrict__ Xb,
                                        const float* plane, const int* lut,
                                        int m, int row) {
    if (row < Cn) return Xb[(size_t)row * HWn + m];
    return plane[lut[row - Cn] + m];
}

__global__ __launch_bounds__(512, 4) void k_energy(
    const float* __restrict__ X,
    const float* __restrict__ Wv,
    const float* __restrict__ query,
    const unsigned short* __restrict__ Bfr,
    const float* __restrict__ mask,
    const float* __restrict__ asum,
    float* __restrict__ energy,      // out: expmask
    float* __restrict__ denom)
{
    __shared__ __align__(16) unsigned short As[4][64 * 42];   // 43,008B
    __shared__ float plane[878];          // 814 im2col + 64 zero pad
    __shared__ int   lut[148];            // row-684 -> plane offset (or pad)
    __shared__ float qs[512];
    __shared__ float wvs[512];
    __shared__ float red[8][64];

    const int t = threadIdx.x;
    const int d = blockIdx.x;
    // bijective XCD swizzle: 64 blocks (4 batches x 16 hh) per XCD
    const int xcd = d & 7, idx = d >> 3;
    const int b = xcd * 4 + (idx >> 4), hh = idx & 15;
    const int w = t >> 6, lane = t & 63;
    const int q = lane >> 4, r = lane & 15;
    const int mA = lane;                   // staging: m index; wave w -> k rows w*8..w*8+7

    const float* Xb = X + (size_t)b * Cn * HWn + hh * Wn;
    const unsigned short* Bp = Bfr + (size_t)(w * 4) * 26 * 512;

    // ---- prologue: plane(+zero pad) / lut / qs / wvs
    for (int i = t; i < 878; i += 512) {
        float v = 0.f;
        if (i < 814) {
            int di = i / 74, cc = i - di * 74;
            int h2 = hh + di - 5, w2 = cc - 5;
            if (h2 >= 0 && h2 < Hn && w2 >= 0 && w2 < Wn)
                v = asum[b * HWn + h2 * Wn + w2];
        }
        plane[i] = v;
    }
    if (t < 148) {
        int off = 814;                    // zero-pad region
        if (t < 121) { int di = t / 11; off = di * 74 + (t - di * 11); }
        lut[t] = off;
    }
    qs[t]  = query[b * An + t];
    wvs[t] = Wv[t];

    short8 bf[4], af[4];
    float va[8];

    // stage chunks 0,1 (rows 0..63, pure X): wave w -> rows w*8..w*8+7
    {
        const float* xp = Xb + (size_t)(w * 8) * HWn + mA;
        #pragma unroll
        for (int j = 0; j < 8; ++j) va[j] = xp[(size_t)j * HWn];
        uint4 u;
        u.x = cvt2(va[0], va[1]); u.y = cvt2(va[2], va[3]);
        u.z = cvt2(va[4], va[5]); u.w = cvt2(va[6], va[7]);
        *(uint4*)&As[w >> 2][mA * 42 + ((w * 8) & 31)] = u;
    }
    // va <- chunks 2,3 data (rows 64..127, pure X); then bf <- B(0)
    {
        const float* xp = Xb + (size_t)(64 + w * 8) * HWn + mA;
        #pragma unroll
        for (int j = 0; j < 8; ++j) va[j] = xp[(size_t)j * HWn];
    }
    #pragma unroll
    for (int nf = 0; nf < 4; ++nf)
        bf[nf] = *(const short8*)(Bp + ((size_t)(nf * 26)) * 512 + lane * 8);
    __syncthreads();   // prologue: full drain once is fine

    floatx4 acc[4][4];
    #pragma unroll
    for (int mf = 0; mf < 4; ++mf)
        #pragma unroll
        for (int nf = 0; nf < 4; ++nf)
            acc[mf][nf] = (floatx4){0.f, 0.f, 0.f, 0.f};

#define READA(BUF) {                                                          \
    _Pragma("unroll")                                                         \
    for (int mf = 0; mf < 4; ++mf)                                            \
        af[mf] = *(const short8*)&As[BUF][(mf * 16 + r) * 42 + q * 8];        \
    }

#define WRITEA2(WB) {                                                         \
    uint4 u;                                                                  \
    u.x = cvt2(va[0], va[1]); u.y = cvt2(va[2], va[3]);                       \
    u.z = cvt2(va[4], va[5]); u.w = cvt2(va[6], va[7]);                       \
    *(uint4*)&As[(WB) + (w >> 2)][mA * 42 + ((w * 8) & 31)] = u;              \
    }

#define MFMA16() {                                                            \
    __builtin_amdgcn_s_setprio(1);                                            \
    _Pragma("unroll")                                                         \
    for (int mf = 0; mf < 4; ++mf)                                            \
        _Pragma("unroll")                                                     \
        for (int nf = 0; nf < 4; ++nf)                                        \
            acc[mf][nf] = __builtin_amdgcn_mfma_f32_16x16x32_bf16(            \
                af[mf], bf[nf], acc[mf][nf], 0, 0, 0);                        \
    __builtin_amdgcn_s_setprio(0);                                            \
    }

#define ISSUE_BF(CC) {                                                        \
    _Pragma("unroll")                                                         \
    for (int nf = 0; nf < 4; ++nf)                                            \
        bf[nf] = *(const short8*)(Bp + ((size_t)(nf * 26 + (CC))) * 512       \
                                     + lane * 8);                             \
    }

#define ISSUE_VA(S) {                                                         \
    const int base = (2 * (S) + 4) * 32 + w * 8;                              \
    if ((S) <= 7) {                                                           \
        const float* xp = Xb + (size_t)base * HWn + mA;                       \
        _Pragma("unroll")                                                     \
        for (int j = 0; j < 8; ++j) va[j] = xp[(size_t)j * HWn];              \
    } else {                                                                  \
        _Pragma("unroll")                                                     \
        for (int j = 0; j < 8; ++j)                                           \
            va[j] = fetchU(Xb, plane, lut, mA, base + j);                     \
    } }

#define LOOP_BARRIER() {                                                      \
    asm volatile("s_waitcnt lgkmcnt(0)" ::: "memory");                        \
    __builtin_amdgcn_sched_barrier(0);                                        \
    __builtin_amdgcn_s_barrier();                                             \
    __builtin_amdgcn_sched_barrier(0);                                        \
    }

    // ---- 13 super-chunks, ONE barrier each
    for (int s = 0; s < 13; ++s) {
        const int rb = (s & 1) << 1;      // read bufs rb, rb+1
        READA(rb);                        // af <- chunk 2s
        if (s < 12) WRITEA2(rb ^ 2);      // chunks 2s+2,2s+3 (va: counted vmcnt)
        MFMA16();                         // chunk 2s (bf from prev super)
        ISSUE_BF(2 * s + 1);              // bf regs free after MFMA h0
        if (s < 11) ISSUE_VA(s);          // va regs free after WRITEA2
        READA(rb + 1);                    // af <- chunk 2s+1
        MFMA16();                         // chunk 2s+1 (bf ~200cy old: L2-covered)
        if (s < 12) ISSUE_BF(2 * s + 2);  // bf for next super's h0
        LOOP_BARRIER();
    }

#undef READA
#undef WRITEA2
#undef MFMA16
#undef ISSUE_BF
#undef ISSUE_VA
#undef LOOP_BARRIER

    // ---- epilogue: per-mf reduction (spill-free), fused exp/mask/denom
    #pragma unroll
    for (int mf = 0; mf < 4; ++mf) {
        float ep4[4];
        #pragma unroll
        for (int rg = 0; rg < 4; ++rg) ep4[rg] = 0.f;
        #pragma unroll
        for (int nf = 0; nf < 4; ++nf) {
            int nl = w * 64 + nf * 16 + r;
            float qv = qs[nl], wv = wvs[nl];
            #pragma unroll
            for (int rg = 0; rg < 4; ++rg) {
                float x = acc[mf][nf][rg] + qv;
                float e2 = __expf(2.f * x);
                float th = 1.f - 2.f * __builtin_amdgcn_rcpf(e2 + 1.f);
                ep4[rg] = fmaf(wv, th, ep4[rg]);
            }
        }
        #pragma unroll
        for (int rg = 0; rg < 4; ++rg) {
            #pragma unroll
            for (int msk = 1; msk <= 8; msk <<= 1)
                ep4[rg] += __shfl_xor(ep4[rg], msk, 64);
        }
        if (r == 0) {
            #pragma unroll
            for (int rg = 0; rg < 4; ++rg)
                red[w][mf * 16 + q * 4 + rg] = ep4[rg];
        }
    }
    __syncthreads();
    if (t < 64) {
        float s = 0.f;
        #pragma unroll
        for (int ww = 0; ww < 8; ++ww) s += red[ww][t];
        // expmask = exp(e)*mask (global max-subtract & bv cancel in alpha)
        float em = __expf(s) * mask[b * HWn + hh * Wn + t];
        energy[b * HWn + hh * Wn + t] = em;
        float ds = em;
        #pragma unroll
        for (int off = 32; off >= 1; off >>= 1)
            ds += __shfl_down(ds, off, 64);
        if (t == 0) atomicAdd(&denom[b], ds);
    }
}

// ---------------------------------------------------------------------------
// K_ctx v4 (R10-proven): 16 channels/block, alpha staged once per 16 ch.
__global__ __launch_bounds__(256) void k_ctx(
    const float* __restrict__ X,
    const float* __restrict__ expmask,
    const float* __restrict__ denom,
    const float* __restrict__ asum,
    float* __restrict__ out)
{
    __shared__ float al[1024];
    const int bx = blockIdx.x, b = blockIdx.y;
    const int t = threadIdx.x, lane = t & 63, wid = t >> 6;

    const float rd = 1.f / denom[b];
    #pragma unroll
    for (int i = 0; i < 4; ++i)
        al[i * 256 + t] = expmask[b * HWn + i * 256 + t] * rd;
    __syncthreads();

    const int c0 = bx * 16 + wid * 4;
    const float* xpc[4];
    #pragma unroll
    for (int cc = 0; cc < 4; ++cc) {
        int c = c0 + cc; if (c >= Cn) c = Cn - 1;    // clamp (dup ch, no OOB)
        xpc[cc] = X + ((size_t)(b * Cn + c)) * HWn;
    }
    float s0 = 0.f, s1 = 0.f, s2 = 0.f, s3 = 0.f;
    #pragma unroll
    for (int i = 0; i < 4; ++i) {
        const int off = i * 256 + lane * 4;
        float4 a = *(const float4*)(al + off);
        float4 x0 = *(const float4*)(xpc[0] + off);
        float4 x1 = *(const float4*)(xpc[1] + off);
        float4 x2 = *(const float4*)(xpc[2] + off);
        float4 x3 = *(const float4*)(xpc[3] + off);
        s0 = fmaf(a.x, x0.x, s0); s0 = fmaf(a.y, x0.y, s0);
        s0 = fmaf(a.z, x0.z, s0); s0 = fmaf(a.w, x0.w, s0);
        s1 = fmaf(a.x, x1.x, s1); s1 = fmaf(a.y, x1.y, s1);
        s1 = fmaf(a.z, x1.z, s1); s1 = fmaf(a.w, x1.w, s1);
        s2 = fmaf(a.x, x2.x, s2); s2 = fmaf(a.y, x2.y, s2);
        s2 = fmaf(a.z, x2.z, s2); s2 = fmaf(a.w, x2.w, s2);
        s3 = fmaf(a.x, x3.x, s3); s3 = fmaf(a.y, x3.y, s3);
        s3 = fmaf(a.z, x3.z, s3); s3 = fmaf(a.w, x3.w, s3);
    }
    float sv[4] = {s0, s1, s2, s3};
    #pragma unroll
    for (int cc = 0; cc < 4; ++cc) {
        float s = sv[cc];
        #pragma unroll
        for (int off = 32; off >= 1; off >>= 1)
            s += __shfl_down(s, off, 64);
        if (lane == 0 && c0 + cc < Cn) out[b * Cn + c0 + cc] = s;
    }

    if (bx == 0) {
        #pragma unroll
        for (int i = 0; i < 4; ++i) {
            int p = i * 256 + t;
            float a = al[p];
            out[OUT_ALPHA + b * HWn + p] = a;
            out[OUT_ASUM  + b * HWn + p] = a + asum[b * HWn + p];
        }
    }
}

// ---------------------------------------------------------------------------
extern "C" void kernel_launch(void* const* d_in, const int* in_sizes, int n_in,
                              void* d_out, int out_size, void* d_ws, size_t ws_size,
                              hipStream_t stream)
{
    const float* X      = (const float*)d_in[0];
    const float* hidden = (const float*)d_in[1];
    const float* asum   = (const float*)d_in[2];
    const float* mask   = (const float*)d_in[3];
    const float* Wh     = (const float*)d_in[4];
    const float* bh     = (const float*)d_in[5];
    const float* Wec    = (const float*)d_in[6];
    const float* bec    = (const float*)d_in[7];
    const float* Wac    = (const float*)d_in[8];
    const float* Waw    = (const float*)d_in[9];
    const float* Wv     = (const float*)d_in[10];
    (void)in_sizes; (void)n_in; (void)out_size; (void)ws_size;

    float* out = (float*)d_out;
    float* ws = (float*)d_ws;
    float* query  = ws;                                    // 16384 floats
    float* energy = ws + 16384;                            // 32768 (expmask)
    float* denom  = ws + 16384 + 32768;                    // 32 floats (+pad 64)
    unsigned short* Bfr = (unsigned short*)(ws + 16384 + 32768 + 64); // 512*832 bf16

    k_prep   <<<dim3(576),      dim3(256), 0, stream>>>(hidden, Wh, bh, bec,
                                                        Wec, Wac, Waw, query, Bfr, denom);
    k_energy <<<dim3(512),      dim3(512), 0, stream>>>(X, Wv, query, Bfr,
                                                        mask, asum, energy, denom);
    k_ctx    <<<dim3(43, 32),   dim3(256), 0, stream>>>(X, energy, denom, asum, out);
}